// Round 5
// baseline (794.083 us; speedup 1.0000x reference)
//
#include <hip/hip_runtime.h>
#include <hip/hip_bf16.h>
#include <math.h>

// Problem constants
#define NKH 16
#define NVH 32
#define DKD 128
#define DVD 128
#define CDIM 2048
#define KEY_DIM 2048   // NK*DK
#define VAL_DIM 4096   // NV*DV
#define CONV_DIM 8192  // 2*KEY_DIM+VAL_DIM
#define BB 2
#define TT 2048
#define MROWS 4096     // B*T
#define CH 64          // recurrence chunk length
#define NCHUNK 32      // TT/CH

typedef unsigned short u16;
typedef __bf16 bf16x8 __attribute__((ext_vector_type(8)));
typedef float f32x4 __attribute__((ext_vector_type(4)));

__device__ __forceinline__ u16 f2bf(float f) {
    union { float f; unsigned u; } a; a.f = f;
    unsigned u = a.u;
    u += 0x7fffu + ((u >> 16) & 1u);
    return (u16)(u >> 16);
}
__device__ __forceinline__ float bf2f(u16 h) {
    union { unsigned u; float f; } a; a.u = ((unsigned)h) << 16;
    return a.f;
}
union BF8 { bf16x8 v; uint2 u2[2]; uint4 u4; u16 s[8]; };
__device__ __forceinline__ bf16x8 lds_ld8(const u16* p) {
    BF8 t; t.u2[0] = *(const uint2*)p; t.u2[1] = *(const uint2*)(p + 4); return t.v;
}
__device__ __forceinline__ bf16x8 lds_ld16(const u16* p) {   // 16B-aligned
    BF8 t; t.u4 = *(const uint4*)p; return t.v;
}
__device__ __forceinline__ void lds_st8(u16* p, uint4 v) {
    *(uint2*)p = make_uint2(v.x, v.y); *(uint2*)(p + 4) = make_uint2(v.z, v.w);
}

// XCD-aware bijective swizzle (kept; neutral measured, harmless)
__device__ __forceinline__ void xcd_swizzle(int& tx, int& ty) {
    const int nx = gridDim.x, ny = gridDim.y;
    const int b  = blockIdx.x + nx * blockIdx.y;
    const int nb = nx * ny;
    if (nx >= 8 && (nx & 7) == 0 && (nb & 255) == 0) {
        const int rnd  = b >> 8;          // wave of 256 blocks
        const int idx  = b & 255;
        const int xcd  = idx & 7;
        const int slot = idx >> 3;        // 0..31 (CU slot within XCD)
        const int RX   = nx >> 3;         // regions across x (1,2,4 for nx=8,16,32)
        const int rx   = xcd & (RX - 1);
        const int ry   = xcd >> __popc(RX - 1);
        tx = rx * 8 + (slot & 7);
        ty = rnd * (256 / nx) + ry * 4 + (slot >> 3);
    } else {
        tx = blockIdx.x; ty = blockIdx.y;
    }
}

// ---------------- diagnostic fill (used only if ws_size too small) -------------
__global__ __launch_bounds__(256) void fill_kernel(float* __restrict__ p, float v, int n) {
    int i = blockIdx.x * 256 + threadIdx.x;
    if (i < n) p[i] = v;
}

// ---------------- cast fp32 -> bf16 (x4 vectorized) ----------------
__global__ __launch_bounds__(256) void cast_kernel(const float* __restrict__ src,
                                                   u16* __restrict__ dst, int n4) {
    int i = blockIdx.x * 256 + threadIdx.x;
    if (i >= n4) return;
    float4 v = ((const float4*)src)[i];
    ushort4 r;
    r.x = f2bf(v.x); r.y = f2bf(v.y); r.z = f2bf(v.z); r.w = f2bf(v.w);
    ((ushort4*)dst)[i] = r;
}

// ---------------- bf16 NT GEMM: C[M,N] = A[M,K] * B[N,K]^T (m97 structure) ------
// 128^2 tile, 32 KB LDS -> multi-block/CU TLP. Used for the beta/g GEMM (N=128)
// and the out-projection (N=2048). NOW with T2 involution swizzle (R2-verified
// pattern): linear wave-uniform gload_lds dest + source col-granule ^= (row&7)
// + reader slot ^= (l15&7). Removes the 5e7 bank conflicts seen in R0.
template<int OUT_BF16>
__global__ __launch_bounds__(256) void gemm_nt(const u16* __restrict__ A,
                                               const u16* __restrict__ Bm,
                                               void* __restrict__ Cv,
                                               int M, int N, int K) {
    __shared__ __align__(16) u16 As[128 * 64];
    __shared__ __align__(16) u16 Bs[128 * 64];
    const int tid  = threadIdx.x;
    const int lane = tid & 63;
    const int wave = tid >> 6;
    int tx, ty;
    xcd_swizzle(tx, ty);
    const int m0 = ty * 128;
    const int n0 = tx * 128;
    const int wm = (wave & 1) * 64;
    const int wn = (wave >> 1) * 64;
    const int l15  = lane & 15;
    const int quad = lane >> 4;

    f32x4 acc[4][4];
#pragma unroll
    for (int i = 0; i < 4; ++i)
#pragma unroll
        for (int j = 0; j < 4; ++j) acc[i][j] = (f32x4)0.0f;

    const int crow = tid >> 3;               // staged row within 32-row group
    const int scol = ((tid & 7) ^ (crow & 7)) * 8;   // swizzled source col

    for (int k0 = 0; k0 < K; k0 += 64) {
#pragma unroll
        for (int p = 0; p < 4; ++p) {
            int row = p * 32 + crow;
            const u16* ga = A + (size_t)(m0 + row) * K + k0 + scol;
            char* la = (char*)As + (size_t)(p * 256 + (wave << 6)) * 16;
            __builtin_amdgcn_global_load_lds((const __attribute__((address_space(1))) void*)ga,
                                             (__attribute__((address_space(3))) void*)la, 16, 0, 0);
            const u16* gb = Bm + (size_t)(n0 + row) * K + k0 + scol;
            char* lb = (char*)Bs + (size_t)(p * 256 + (wave << 6)) * 16;
            __builtin_amdgcn_global_load_lds((const __attribute__((address_space(1))) void*)gb,
                                             (__attribute__((address_space(3))) void*)lb, 16, 0, 0);
        }
        __syncthreads();
#pragma unroll
        for (int kk = 0; kk < 64; kk += 32) {
            bf16x8 af[4], bfr[4];
#pragma unroll
            for (int i = 0; i < 4; ++i) {
                int sa = (((kk >> 3) + quad) ^ (l15 & 7)) * 8;   // inverse swizzle
                af[i]  = *(const bf16x8*)&As[(wm + i * 16 + l15) * 64 + sa];
                bfr[i] = *(const bf16x8*)&Bs[(wn + i * 16 + l15) * 64 + sa];
            }
#pragma unroll
            for (int i = 0; i < 4; ++i)
#pragma unroll
                for (int j = 0; j < 4; ++j)
                    acc[i][j] = __builtin_amdgcn_mfma_f32_16x16x32_bf16(af[i], bfr[j], acc[i][j], 0, 0, 0);
        }
        __syncthreads();
    }
#pragma unroll
    for (int i = 0; i < 4; ++i) {
#pragma unroll
        for (int j = 0; j < 4; ++j) {
#pragma unroll
            for (int r = 0; r < 4; ++r) {
                int grow = m0 + wm + i * 16 + quad * 4 + r;
                int gcol = n0 + wn + j * 16 + l15;
                if (OUT_BF16) {
                    ((u16*)Cv)[(size_t)grow * N + gcol] = f2bf(acc[i][j][r]);
                } else {
                    ((float*)Cv)[(size_t)grow * N + gcol] = acc[i][j][r];
                }
            }
        }
    }
}

// ---------------- bf16 NT GEMM, 256x256 tile, 8 waves, BK=32, 4-buf pipeline ----
// T4 done right: stage distance 3 K-tiles; tile-boundary wait is vmcnt(8)
// (tiles T+1,T+2 stay in flight) -> the per-tile full-drain convoy that capped
// R2/R3 at ~900 TF is gone. T2 involution swizzle for BK=32: granule c of row
// holds source col-granule c ^ ((row>>1)&3); reader applies the same XOR
// (verified 2-way bank aliasing = free). Race-freedom: stage(T+3) writes
// buf (T-1)&3, issued only after iter-T's leading barrier (all waves have
// retired their iter-(T-1) ds_reads); read-after-write by vmcnt+barrier.
template<int OUT_BF16>
__global__ __launch_bounds__(512, 2) void gemm_nt_256(const u16* __restrict__ A,
                                                      const u16* __restrict__ Bm,
                                                      void* __restrict__ Cv,
                                                      int M, int N, int K) {
    __shared__ __align__(16) u16 sA[4][256 * 32];   // 4 x 16 KiB
    __shared__ __align__(16) u16 sB[4][256 * 32];   // 4 x 16 KiB
    const int tid  = threadIdx.x;
    const int lane = tid & 63;
    const int wave = tid >> 6;       // 0..7
    const int wr   = wave >> 2;      // 0..1  -> rows [wr*128, +128)
    const int wc   = wave & 3;       // 0..3  -> cols [wc*64,  +64)
    const int l15  = lane & 15;
    const int quad = lane >> 4;
    int tx, ty;
    xcd_swizzle(tx, ty);
    const int m0 = ty * 256;
    const int n0 = tx * 256;

    f32x4 acc[8][4];
#pragma unroll
    for (int i = 0; i < 8; ++i)
#pragma unroll
        for (int j = 0; j < 4; ++j) acc[i][j] = (f32x4)0.0f;

    // Stage one BK=32 K-tile (A: 256x32, B: 256x32 = 16 KB each) into buf.
    // 1024 granules of 16B per matrix; wave w, pass p owns granules
    // [p*512 + w*64, +64), HW writes wave-uniform base + lane*16.
    // granule g: row = g>>2, LDS col-granule c = g&3 holds source granule
    // c ^ ((row>>1)&3)  (involution; reader applies same XOR).
    auto stage = [&](int buf, int kk0) {
#pragma unroll
        for (int p = 0; p < 2; ++p) {
            const int gbase = p * 512 + wave * 64;       // wave-uniform
            const int g   = gbase + lane;
            const int row = g >> 2;                      // 0..255
            const int sc  = ((g & 3) ^ ((row >> 1) & 3)) * 8;
            const u16* ga = A + (size_t)(m0 + row) * K + kk0 + sc;
            __builtin_amdgcn_global_load_lds(
                (const __attribute__((address_space(1))) void*)ga,
                (__attribute__((address_space(3))) void*)((char*)&sA[buf][0] + (size_t)gbase * 16),
                16, 0, 0);
            const u16* gb = Bm + (size_t)(n0 + row) * K + kk0 + sc;
            __builtin_amdgcn_global_load_lds(
                (const __attribute__((address_space(1))) void*)gb,
                (__attribute__((address_space(3))) void*)((char*)&sB[buf][0] + (size_t)gbase * 16),
                16, 0, 0);
        }
    };

    const int NT = K >> 5;            // BK=32
    stage(0, 0);                      // prologue: tiles 0,1,2 -> bufs 0,1,2
    stage(1, 32);
    stage(2, 64);

    const int slot8 = (quad ^ ((l15 >> 1) & 3)) * 8;   // reader inverse swizzle

    for (int T = 0; T < NT; ++T) {
        const int P = T & 3;
        __builtin_amdgcn_sched_barrier(0);
        // Outstanding here: tiles T+1, T+2 (8 loads). Counted wait -> tile T
        // (issued 3 iters ago) is guaranteed landed without draining the queue.
        if (T + 2 < NT)      asm volatile("s_waitcnt vmcnt(8)" ::: "memory");
        else if (T + 1 < NT) asm volatile("s_waitcnt vmcnt(4)" ::: "memory");
        else                 asm volatile("s_waitcnt vmcnt(0)" ::: "memory");
        __builtin_amdgcn_s_barrier();             // buf[P] visible; prior reads retired
        __builtin_amdgcn_sched_barrier(0);
        if (T + 3 < NT) stage((T + 3) & 3, (T + 3) << 5);   // into buf (T-1)&3

        bf16x8 aF[8], bF[4];
#pragma unroll
        for (int j = 0; j < 4; ++j) {
            int row = wc * 64 + j * 16 + l15;
            bF[j] = lds_ld16(&sB[P][row * 32 + slot8]);
        }
#pragma unroll
        for (int i = 0; i < 8; ++i) {
            int row = wr * 128 + i * 16 + l15;
            aF[i] = lds_ld16(&sA[P][row * 32 + slot8]);
        }
        __builtin_amdgcn_s_setprio(1);
#pragma unroll
        for (int i = 0; i < 8; ++i)
#pragma unroll
            for (int j = 0; j < 4; ++j)
                acc[i][j] = __builtin_amdgcn_mfma_f32_16x16x32_bf16(aF[i], bF[j], acc[i][j], 0, 0, 0);
        __builtin_amdgcn_s_setprio(0);
        // no trailing barrier: next iter's leading barrier orders everything.
    }

#pragma unroll
    for (int i = 0; i < 8; ++i) {
#pragma unroll
        for (int j = 0; j < 4; ++j) {
#pragma unroll
            for (int r = 0; r < 4; ++r) {
                int grow = m0 + wr * 128 + i * 16 + quad * 4 + r;
                int gcol = n0 + wc * 64 + j * 16 + l15;
                if (OUT_BF16) {
                    ((u16*)Cv)[(size_t)grow * N + gcol] = f2bf(acc[i][j][r]);
                } else {
                    ((float*)Cv)[(size_t)grow * N + gcol] = acc[i][j][r];
                }
            }
        }
    }
}

// ---------------- beta/g epilogue over bg scores [4096 x 128(64 used)] ----------
__global__ __launch_bounds__(256) void bg_epilogue(const float* __restrict__ scores,
                                                   const float* __restrict__ dt_bias,
                                                   const float* __restrict__ A_log,
                                                   float* __restrict__ beta,
                                                   float* __restrict__ g) {
    int i = blockIdx.x * 256 + threadIdx.x;   // 4096*64
    int row = i >> 6, col = i & 63;
    float s = scores[(size_t)row * 128 + col];
    if (col < 32) {
        beta[(size_t)row * 32 + col] = 1.f / (1.f + __expf(-s));
    } else {
        int h = col - 32;
        float aa = s + dt_bias[h];
        float sp = (aa > 20.f) ? aa : log1pf(__expf(aa));
        g[(size_t)row * 32 + h] = -__expf(A_log[h]) * sp;
    }
}

// ---------------- causal depthwise conv (K=4) + silu -> bf16 ----------------
__global__ __launch_bounds__(256) void conv_silu_kernel(const u16* __restrict__ qkv,
                                                        const float* __restrict__ conv_w,
                                                        const float* __restrict__ conv_state,
                                                        const int* __restrict__ input_pos,
                                                        u16* __restrict__ qkvc) {
    const int d   = blockIdx.x * 256 + threadIdx.x;
    const int row = blockIdx.y;
    const int t   = row & (TT - 1);
    const int b   = row >> 11;
    const float keep = (input_pos[0] == 0) ? 0.f : 1.f;
    float4 w = *(const float4*)&conv_w[(size_t)d * 4];
    float acc = 0.f;
#pragma unroll
    for (int j = 0; j < 4; ++j) {
        int u = t + j - 3;
        float v;
        if (u >= 0) v = bf2f(qkv[(size_t)(b * TT + u) * CONV_DIM + d]);
        else        v = keep * conv_state[((size_t)b * CONV_DIM + d) * 4 + (u + 4)];
        acc += (&w.x)[j] * v;
    }
    float s = acc / (1.f + __expf(-acc));
    qkvc[(size_t)row * CONV_DIM + d] = f2bf(s);
}

// ---------------- q/k L2 normalize in place (bf16) ----------------
__global__ __launch_bounds__(256) void qknorm_kernel(u16* __restrict__ qkvc) {
    const int gid  = blockIdx.x * 4 + (threadIdx.x >> 6);
    const int lane = threadIdx.x & 63;
    const int row  = gid >> 5;
    const int h    = gid & 31;
    u16* p = qkvc + (size_t)row * CONV_DIM + h * 128;
    ushort2 vb = *(ushort2*)&p[lane * 2];
    float v0 = bf2f(vb.x), v1 = bf2f(vb.y);
    float ss = v0 * v0 + v1 * v1;
#pragma unroll
    for (int off = 32; off; off >>= 1) ss += __shfl_xor(ss, off);
    float scale = 1.f / fmaxf(sqrtf(ss), 1e-12f);
    ushort2 r;
    r.x = f2bf(v0 * scale);
    r.y = f2bf(v1 * scale);
    *(ushort2*)&p[lane * 2] = r;
}

// ---------------- K1: per-chunk gate prefix (wave scan, CH=64) ----------------
__global__ __launch_bounds__(64) void gates_kernel(const float* __restrict__ g,
                                                   const float* __restrict__ beta_,
                                                   float* __restrict__ gcum,
                                                   float* __restrict__ qsb,
                                                   float* __restrict__ wkb,
                                                   float* __restrict__ dLb) {
    const int bh = blockIdx.x, c = blockIdx.y;
    const int b = bh >> 5, h = bh & 31;
    const int t = threadIdx.x;
    const int row = b * TT + c * CH + t;
    float G = g[(size_t)row * 32 + h];
#pragma unroll
    for (int off = 1; off < 64; off <<= 1) {
        float x = __shfl_up(G, off);
        if (t >= off) G += x;
    }
    float GL = __shfl(G, 63);
    int oidx = bh * TT + c * CH + t;
    gcum[oidx] = G;
    qsb[oidx] = __expf(G);
    wkb[oidx] = __expf(GL - G) * beta_[(size_t)row * 32 + h];
    if (t == 0) dLb[bh * NCHUNK + c] = __expf(GL);
}

// ---------------- kT transpose: qkvc k-section -> kT[B][NK][DK][T] ----------------
__global__ __launch_bounds__(256) void ktrans_kernel(const u16* __restrict__ qkvc,
                                                     u16* __restrict__ kT) {
    const int id = blockIdx.x;
    const int tt = id & 31, dkh = (id >> 5) & 1, hk = (id >> 6) & 15, b = id >> 10;
    const int t0 = tt * 64, dk0 = dkh * 64;
    __shared__ __align__(16) u16 tile[64 * 68];
#pragma unroll
    for (int it = 0; it < 2; ++it) {
        int idx = it * 256 + threadIdx.x;
        int tl = idx >> 3, c8 = (idx & 7) * 8;
        uint4 v = *(const uint4*)&qkvc[(size_t)(b * TT + t0 + tl) * CONV_DIM + KEY_DIM + hk * 128 + dk0 + c8];
        lds_st8(&tile[tl * 68 + c8], v);
    }
    __syncthreads();
#pragma unroll
    for (int it = 0; it < 2; ++it) {
        int idx = it * 256 + threadIdx.x;
        int dkl = idx >> 3, t8 = (idx & 7) * 8;
        unsigned w[4];
#pragma unroll
        for (int p = 0; p < 4; ++p) {
            unsigned lo = tile[(t8 + 2 * p) * 68 + dkl];
            unsigned hi = tile[(t8 + 2 * p + 1) * 68 + dkl];
            w[p] = lo | (hi << 16);
        }
        *(uint4*)&kT[((size_t)((b * 16 + hk) * 128 + dk0 + dkl)) * TT + t0 + t8] =
            make_uint4(w[0], w[1], w[2], w[3]);
    }
}

// ---------------- K2: chunk state pass + inter output (MFMA) ----------------
__global__ __launch_bounds__(256) void chunk_state_kernel(const u16* __restrict__ qkvc,
                                                          const u16* __restrict__ kT,
                                                          const float* __restrict__ qsb,
                                                          const float* __restrict__ wkb,
                                                          const float* __restrict__ dLb,
                                                          const float* __restrict__ rec_state,
                                                          const int* __restrict__ input_pos,
                                                          u16* __restrict__ o) {
    const int b = blockIdx.x, h = blockIdx.y, dvs = blockIdx.z;
    const int tid = threadIdx.x, lane = tid & 63, wave = tid >> 6;
    const int l15 = lane & 15, quad = lane >> 4;
    const int hq = h >> 1, bh = b * 32 + h;
    const float keep = (input_pos[0] == 0) ? 0.f : 1.f;

    __shared__ __align__(16) u16 sQ[64 * 132];
    __shared__ __align__(16) u16 sKT[128 * 68];
    __shared__ __align__(16) u16 sR[32 * 132];
    __shared__ float sQS[64];

    f32x4 st[2][2];
#pragma unroll
    for (int i = 0; i < 2; ++i)
#pragma unroll
        for (int j = 0; j < 2; ++j)
#pragma unroll
            for (int r = 0; r < 4; ++r) {
                int dv = dvs * 32 + i * 16 + quad * 4 + r;
                int dk = wave * 32 + j * 16 + l15;
                st[i][j][r] = keep * rec_state[((size_t)(bh * 128 + dk)) * 128 + dv];
            }

    for (int c = 0; c < NCHUNK; ++c) {
        const int t0 = c * CH;
#pragma unroll
        for (int i = 0; i < 2; ++i)
#pragma unroll
            for (int j = 0; j < 2; ++j)
#pragma unroll
                for (int r = 0; r < 4; ++r)
                    sR[(i * 16 + quad * 4 + r) * 132 + wave * 32 + j * 16 + l15] = f2bf(st[i][j][r]);
#pragma unroll
        for (int it = 0; it < 4; ++it) {
            int idx = it * 256 + tid;
            int t = idx >> 4, c8 = (idx & 15) * 8;
            uint4 v = *(const uint4*)&qkvc[(size_t)(b * TT + t0 + t) * CONV_DIM + hq * 128 + c8];
            lds_st8(&sQ[t * 132 + c8], v);
        }
        if (tid < 64) sQS[tid] = qsb[bh * TT + t0 + tid];
        __syncthreads();
        {
            f32x4 ao[2] = {(f32x4)0.0f, (f32x4)0.0f};
#pragma unroll
            for (int kk = 0; kk < 4; ++kk) {
                bf16x8 af = lds_ld8(&sQ[(wave * 16 + l15) * 132 + kk * 32 + quad * 8]);
                bf16x8 b0 = lds_ld8(&sR[(l15) * 132 + kk * 32 + quad * 8]);
                bf16x8 b1 = lds_ld8(&sR[(16 + l15) * 132 + kk * 32 + quad * 8]);
                ao[0] = __builtin_amdgcn_mfma_f32_16x16x32_bf16(af, b0, ao[0], 0, 0, 0);
                ao[1] = __builtin_amdgcn_mfma_f32_16x16x32_bf16(af, b1, ao[1], 0, 0, 0);
            }
#pragma unroll
            for (int j = 0; j < 2; ++j)
#pragma unroll
                for (int r = 0; r < 4; ++r) {
                    int t = wave * 16 + quad * 4 + r;
                    int dv = dvs * 32 + j * 16 + l15;
                    o[((size_t)(b * TT + t0 + t) * 32 + h) * 128 + dv] = f2bf(ao[j][r] * sQS[t]);
                }
        }
        __syncthreads();
#pragma unroll
        for (int it = 0; it < 4; ++it) {
            int idx = it * 256 + tid;
            int dk = idx >> 3, t8 = (idx & 7) * 8;
            uint4 v = *(const uint4*)&kT[((size_t)((b * 16 + hq) * 128 + dk)) * TT + t0 + t8];
            lds_st8(&sKT[dk * 68 + t8], v);
        }
        {
            int t = tid >> 2, dvo = (tid & 3) * 8;
            float w = wkb[bh * TT + t0 + t];
            BF8 v;
            v.u4 = *(const uint4*)&qkvc[(size_t)(b * TT + t0 + t) * CONV_DIM + 2 * KEY_DIM + h * 128 + dvs * 32 + dvo];
#pragma unroll
            for (int u = 0; u < 8; ++u)
                sR[(dvo + u) * 68 + t] = f2bf(bf2f(v.s[u]) * w);
        }
        __syncthreads();
        {
            float d = dLb[bh * NCHUNK + c];
#pragma unroll
            for (int i = 0; i < 2; ++i)
#pragma unroll
                for (int j = 0; j < 2; ++j)
#pragma unroll
                    for (int r = 0; r < 4; ++r) st[i][j][r] *= d;
#pragma unroll
            for (int kk = 0; kk < 2; ++kk) {
                bf16x8 af[2], bfv[2];
#pragma unroll
                for (int i = 0; i < 2; ++i)
                    af[i] = lds_ld8(&sR[(i * 16 + l15) * 68 + kk * 32 + quad * 8]);
#pragma unroll
                for (int j = 0; j < 2; ++j)
                    bfv[j] = lds_ld8(&sKT[(wave * 32 + j * 16 + l15) * 68 + kk * 32 + quad * 8]);
#pragma unroll
                for (int i = 0; i < 2; ++i)
#pragma unroll
                    for (int j = 0; j < 2; ++j)
                        st[i][j] = __builtin_amdgcn_mfma_f32_16x16x32_bf16(af[i], bfv[j], st[i][j], 0, 0, 0);
            }
        }
        __syncthreads();
    }
}

// ---------------- K3: intra-chunk causal attention (MFMA), adds into o ----------------
__global__ __launch_bounds__(256) void chunk_intra_kernel(const u16* __restrict__ qkvc,
                                                          const float* __restrict__ gcum,
                                                          const float* __restrict__ beta_,
                                                          u16* __restrict__ o) {
    const int b = blockIdx.x, h = blockIdx.y, c = blockIdx.z;
    const int tid = threadIdx.x, lane = tid & 63, wave = tid >> 6;
    const int l15 = lane & 15, quad = lane >> 4;
    const int hq = h >> 1, bh = b * 32 + h;
    const int t0 = c * CH;

    __shared__ __align__(16) u16 sQ[64 * 132];
    __shared__ __align__(16) u16 sK[64 * 132];
    __shared__ __align__(16) u16 sVT[128 * 68];
    __shared__ float sG[64];
    __shared__ float sB[64];

#pragma unroll
    for (int it = 0; it < 4; ++it) {
        int idx = it * 256 + tid;
        int t = idx >> 4, c8 = (idx & 15) * 8;
        size_t rbase = (size_t)(b * TT + t0 + t) * CONV_DIM;
        lds_st8(&sQ[t * 132 + c8], *(const uint4*)&qkvc[rbase + hq * 128 + c8]);
        lds_st8(&sK[t * 132 + c8], *(const uint4*)&qkvc[rbase + KEY_DIM + hq * 128 + c8]);
    }
    if (tid < 64) {
        sG[tid] = gcum[bh * TT + t0 + tid];
        sB[tid] = beta_[(size_t)(b * TT + t0 + tid) * 32 + h];
    }
    __syncthreads();
    const int wm = (wave & 1) * 32, wn = (wave >> 1) * 32;
    f32x4 acc[2][2];
#pragma unroll
    for (int i = 0; i < 2; ++i)
#pragma unroll
        for (int j = 0; j < 2; ++j) acc[i][j] = (f32x4)0.0f;
#pragma unroll
    for (int kk = 0; kk < 4; ++kk) {
        bf16x8 af[2], bfv[2];
#pragma unroll
        for (int i = 0; i < 2; ++i) {
            af[i]  = lds_ld8(&sQ[(wm + i * 16 + l15) * 132 + kk * 32 + quad * 8]);
            bfv[i] = lds_ld8(&sK[(wn + i * 16 + l15) * 132 + kk * 32 + quad * 8]);
        }
#pragma unroll
        for (int i = 0; i < 2; ++i)
#pragma unroll
            for (int j = 0; j < 2; ++j)
                acc[i][j] = __builtin_amdgcn_mfma_f32_16x16x32_bf16(af[i], bfv[j], acc[i][j], 0, 0, 0);
    }
    __syncthreads();
#pragma unroll
    for (int i = 0; i < 2; ++i)
#pragma unroll
        for (int j = 0; j < 2; ++j)
#pragma unroll
            for (int r = 0; r < 4; ++r) {
                int t = wm + i * 16 + quad * 4 + r;
                int s = wn + j * 16 + l15;
                float av = 0.f;
                if (s <= t) av = __expf(sG[t] - sG[s]) * sB[s] * acc[i][j][r];
                ((u16*)sQ)[t * 68 + s] = f2bf(av);
            }
#pragma unroll
    for (int it = 0; it < 4; ++it) {
        int idx = it * 256 + tid;
        int t = idx >> 4, c8 = (idx & 15) * 8;
        lds_st8(&sK[t * 132 + c8],
                *(const uint4*)&qkvc[(size_t)(b * TT + t0 + t) * CONV_DIM + 2 * KEY_DIM + h * 128 + c8]);
    }
    __syncthreads();
    {
        int dv = (wave & 1) * 64 + lane;
        int tb = (wave >> 1) * 32;
#pragma unroll
        for (int tc = 0; tc < 4; ++tc) {
            int t8 = tb + tc * 8;
            unsigned w[4];
#pragma unroll
            for (int p = 0; p < 4; ++p) {
                unsigned lo = sK[(t8 + 2 * p) * 132 + dv];
                unsigned hi = sK[(t8 + 2 * p + 1) * 132 + dv];
                w[p] = lo | (hi << 16);
            }
            lds_st8(&sVT[dv * 68 + t8], make_uint4(w[0], w[1], w[2], w[3]));
        }
    }
    __syncthreads();
    const int wm2 = (wave & 1) * 32, wn2 = (wave >> 1) * 64;
    f32x4 oacc[2][4];
#pragma unroll
    for (int i = 0; i < 2; ++i)
#pragma unroll
        for (int j = 0; j < 4; ++j) oacc[i][j] = (f32x4)0.0f;
#pragma unroll
    for (int kk = 0; kk < 2; ++kk) {
        bf16x8 af[2], bfv[4];
#pragma unroll
        for (int i = 0; i < 2; ++i)
            af[i] = lds_ld8(&((u16*)sQ)[(wm2 + i * 16 + l15) * 68 + kk * 32 + quad * 8]);
#pragma unroll
        for (int j = 0; j < 4; ++j)
            bfv[j] = lds_ld8(&sVT[(wn2 + j * 16 + l15) * 68 + kk * 32 + quad * 8]);
#pragma unroll
        for (int i = 0; i < 2; ++i)
#pragma unroll
            for (int j = 0; j < 4; ++j)
                oacc[i][j] = __builtin_amdgcn_mfma_f32_16x16x32_bf16(af[i], bfv[j], oacc[i][j], 0, 0, 0);
    }
#pragma unroll
    for (int i = 0; i < 2; ++i)
#pragma unroll
        for (int j = 0; j < 4; ++j)
#pragma unroll
            for (int r = 0; r < 4; ++r) {
                int t = wm2 + i * 16 + quad * 4 + r;
                int dv = wn2 + j * 16 + l15;
                size_t addr = ((size_t)(b * TT + t0 + t) * 32 + h) * 128 + dv;
                o[addr] = f2bf(oacc[i][j][r] + bf2f(o[addr]));
            }
}

// ---------------- gated RMSNorm: o *= silu(z); rmsnorm; -> bf16 ----------------
__global__ __launch_bounds__(256) void gnorm_kernel(const u16* __restrict__ o,
                                                    const u16* __restrict__ zb,
                                                    const float* __restrict__ norm_w,
                                                    u16* __restrict__ ob) {
    const int gid  = blockIdx.x * 4 + (threadIdx.x >> 6);
    const int lane = threadIdx.x & 63;
    const int row  = gid >> 5;
    const int h    = gid & 31;
    const size_t base = ((size_t)row * NVH + h) * DVD;
    ushort2 oraw = *(const ushort2*)&o[base + lane * 2];
    float o0 = bf2f(oraw.x), o1 = bf2f(oraw.y);
    float z0 = bf2f(zb[base + lane * 2]);
    float z1 = bf2f(zb[base + lane * 2 + 1]);
    o0 *= z0 / (1.f + __expf(-z0));
    o1 *= z1 / (1.f + __expf(-z1));
    float ss = o0 * o0 + o1 * o1;
#pragma unroll
    for (int off = 32; off; off >>= 1) ss += __shfl_xor(ss, off);
    float scale = rsqrtf(ss * (1.f / 128.f) + 1e-6f);
    float w0 = norm_w[lane * 2], w1 = norm_w[lane * 2 + 1];
    ushort2 r;
    r.x = f2bf(o0 * scale * w0);
    r.y = f2bf(o1 * scale * w1);
    *(ushort2*)&ob[base + lane * 2] = r;
}

extern "C" void kernel_launch(void* const* d_in, const int* in_sizes, int n_in,
                              void* d_out, int out_size, void* d_ws, size_t ws_size,
                              hipStream_t stream) {
    const float* x         = (const float*)d_in[0];
    const int*   input_pos = (const int*)d_in[1];
    const float* W_qkv     = (const float*)d_in[2];
    const float* W_z       = (const float*)d_in[3];
    const float* W_b       = (const float*)d_in[4];
    const float* W_a       = (const float*)d_in[5];
    const float* conv_w    = (const float*)d_in[6];
    const float* dt_bias   = (const float*)d_in[7];
    const float* A_log     = (const float*)d_in[8];
    const float* norm_w    = (const float*)d_in[9];
    const float* W_out     = (const float*)d_in[10];
    const float* conv_state = (const float*)d_in[11];
    const float* rec_state  = (const float*)d_in[12];
    float* out = (float*)d_out;

    const size_t REQUIRED = 168820736;   // 161 MiB
    if (ws_size < REQUIRED) {
        float mib = (float)((double)ws_size / 1048576.0);
        fill_kernel<<<(out_size + 255) / 256, 256, 0, stream>>>(out, mib, out_size);
        return;
    }

    // Workspace layout (161 MiB):
    //  [0,64Mi):   xb[0,16)|wqkvb[16,48)|wzb[48,64)
    //              -> after GEMMs: wbab@16Mi (0.5Mi) + bgscores@17Mi (2Mi)
    //              -> qkvc (conv out) -> ob[0,32)+woutb[32,48)
    //  [64,96Mi):  zb
    //  [96,160Mi): qkvb (pre-conv) -> { o[96,128), kT[128,144), gates[144,146) }
    //  [160,161Mi): beta | g
    const size_t MI = 1048576;
    char* ws = (char*)d_ws;
    u16* xb    = (u16*)(ws);
    u16* wqkvb = (u16*)(ws + 16 * MI);
    u16* wzb   = (u16*)(ws + 48 * MI);
    u16* wbab  = (u16*)(ws + 16 * MI);      // 128x2048 bf16, alias dead wqkvb
    float* bgs = (float*)(ws + 17 * MI);    // 4096x128 fp32 scores
    u16* qkvc  = (u16*)(ws);
    u16* ob    = (u16*)(ws);
    u16* woutb = (u16*)(ws + 32 * MI);
    u16* zb    = (u16*)(ws + 64 * MI);
    u16* qkvb  = (u16*)(ws + 96 * MI);
    u16* o     = (u16*)(ws + 96 * MI);
    u16* kT    = (u16*)(ws + 128 * MI);
    float* gcum = (float*)(ws + 144 * MI);
    float* qsb  = (float*)(ws + 144 * MI + 524288);
    float* wkb  = (float*)(ws + 145 * MI);
    float* dLb  = (float*)(ws + 145 * MI + 524288);
    float* beta = (float*)(ws + 160 * MI);
    float* g    = (float*)(ws + 160 * MI + 524288);

    // 1. casts
    cast_kernel<<<8192,  256, 0, stream>>>(x,     xb,    2097152);
    cast_kernel<<<16384, 256, 0, stream>>>(W_qkv, wqkvb, 4194304);
    cast_kernel<<<8192,  256, 0, stream>>>(W_z,   wzb,   2097152);

    // 2. big projections: 256x256-tile BK=32 4-buf pipeline + XCD swizzle
    gemm_nt_256<1><<<dim3(32, 16), 512, 0, stream>>>(xb, wqkvb, qkvb, MROWS, CONV_DIM, CDIM);
    gemm_nt_256<1><<<dim3(16, 16), 512, 0, stream>>>(xb, wzb,   zb,   MROWS, VAL_DIM,  CDIM);

    // 3. beta/g via MFMA GEMM (into dead wqkvb region; before conv clobbers xb)
    cast_kernel<<<256, 256, 0, stream>>>(W_b, wbab, 16384);
    cast_kernel<<<256, 256, 0, stream>>>(W_a, wbab + 65536, 16384);
    hipMemsetAsync(wbab + 131072, 0, 131072 * sizeof(u16), stream);   // pad rows 64..127
    gemm_nt<0><<<dim3(1, 32), 256, 0, stream>>>(xb, wbab, bgs, MROWS, 128, CDIM);
    bg_epilogue<<<1024, 256, 0, stream>>>(bgs, dt_bias, A_log, beta, g);

    // 4. conv + silu (clobbers [0,64Mi)), q/k norm
    conv_silu_kernel<<<dim3(32, 4096), 256, 0, stream>>>(qkvb, conv_w, conv_state, input_pos, qkvc);
    qknorm_kernel<<<32768, 256, 0, stream>>>(qkvc);

    // 5. chunked recurrence
    gates_kernel<<<dim3(64, NCHUNK), 64, 0, stream>>>(g, beta, gcum, qsb, wkb, dLb);
    ktrans_kernel<<<2048, 256, 0, stream>>>(qkvc, kT);
    chunk_state_kernel<<<dim3(BB, NVH, 4), 256, 0, stream>>>(qkvc, kT, qsb, wkb, dLb,
                                                             rec_state, input_pos, o);
    chunk_intra_kernel<<<dim3(BB, NVH, NCHUNK), 256, 0, stream>>>(qkvc, gcum, beta, o);

    // 6. W_out cast (into dead qkvc region) + gated RMSNorm
    cast_kernel<<<8192, 256, 0, stream>>>(W_out, woutb, 2097152);
    gnorm_kernel<<<32768, 256, 0, stream>>>(o, zb, norm_w, ob);

    // 7. output projection (fp32 out; N=2048, 128-tile kernel, now conflict-free)
    gemm_nt<0><<<dim3(16, 32), 256, 0, stream>>>(ob, woutb, out, MROWS, CDIM, VAL_DIM);
}

// Round 7
// 762.264 us; speedup vs baseline: 1.0417x; 1.0417x over previous
//
#include <hip/hip_runtime.h>
#include <hip/hip_bf16.h>
#include <math.h>

// Problem constants
#define NKH 16
#define NVH 32
#define DKD 128
#define DVD 128
#define CDIM 2048
#define KEY_DIM 2048   // NK*DK
#define VAL_DIM 4096   // NV*DV
#define CONV_DIM 8192  // 2*KEY_DIM+VAL_DIM
#define BB 2
#define TT 2048
#define MROWS 4096     // B*T
#define CH 64          // recurrence chunk length
#define NCHUNK 32      // TT/CH

typedef unsigned short u16;
typedef __bf16 bf16x8 __attribute__((ext_vector_type(8)));
typedef float f32x4 __attribute__((ext_vector_type(4)));

__device__ __forceinline__ u16 f2bf(float f) {
    union { float f; unsigned u; } a; a.f = f;
    unsigned u = a.u;
    u += 0x7fffu + ((u >> 16) & 1u);
    return (u16)(u >> 16);
}
__device__ __forceinline__ float bf2f(u16 h) {
    union { unsigned u; float f; } a; a.u = ((unsigned)h) << 16;
    return a.f;
}
union BF8 { bf16x8 v; uint2 u2[2]; uint4 u4; u16 s[8]; };
__device__ __forceinline__ bf16x8 lds_ld8(const u16* p) {
    BF8 t; t.u2[0] = *(const uint2*)p; t.u2[1] = *(const uint2*)(p + 4); return t.v;
}
__device__ __forceinline__ bf16x8 lds_ld16(const u16* p) {   // 16B-aligned
    BF8 t; t.u4 = *(const uint4*)p; return t.v;
}
__device__ __forceinline__ void lds_st8(u16* p, uint4 v) {
    *(uint2*)p = make_uint2(v.x, v.y); *(uint2*)(p + 4) = make_uint2(v.z, v.w);
}

// XCD-aware bijective swizzle (neutral measured, harmless)
__device__ __forceinline__ void xcd_swizzle(int& tx, int& ty) {
    const int nx = gridDim.x, ny = gridDim.y;
    const int b  = blockIdx.x + nx * blockIdx.y;
    const int nb = nx * ny;
    if (nx >= 8 && (nx & 7) == 0 && (nb & 255) == 0) {
        const int rnd  = b >> 8;
        const int idx  = b & 255;
        const int xcd  = idx & 7;
        const int slot = idx >> 3;
        const int RX   = nx >> 3;
        const int rx   = xcd & (RX - 1);
        const int ry   = xcd >> __popc(RX - 1);
        tx = rx * 8 + (slot & 7);
        ty = rnd * (256 / nx) + ry * 4 + (slot >> 3);
    } else {
        tx = blockIdx.x; ty = blockIdx.y;
    }
}

// ---------------- diagnostic fill (used only if ws_size too small) -------------
__global__ __launch_bounds__(256) void fill_kernel(float* __restrict__ p, float v, int n) {
    int i = blockIdx.x * 256 + threadIdx.x;
    if (i < n) p[i] = v;
}

// ---------------- cast fp32 -> bf16 (x4 vectorized) ----------------
__global__ __launch_bounds__(256) void cast_kernel(const float* __restrict__ src,
                                                   u16* __restrict__ dst, int n4) {
    int i = blockIdx.x * 256 + threadIdx.x;
    if (i >= n4) return;
    float4 v = ((const float4*)src)[i];
    ushort4 r;
    r.x = f2bf(v.x); r.y = f2bf(v.y); r.z = f2bf(v.z); r.w = f2bf(v.w);
    ((ushort4*)dst)[i] = r;
}

// ---------------- bf16 NT GEMM: C[M,N] = A[M,K] * B[N,K]^T (m97 structure) ------
// 128^2 tile, swizzled (R5: helped out-proj/bg). Kept for beta/g + out-proj.
template<int OUT_BF16>
__global__ __launch_bounds__(256) void gemm_nt(const u16* __restrict__ A,
                                               const u16* __restrict__ Bm,
                                               void* __restrict__ Cv,
                                               int M, int N, int K) {
    __shared__ __align__(16) u16 As[128 * 64];
    __shared__ __align__(16) u16 Bs[128 * 64];
    const int tid  = threadIdx.x;
    const int lane = tid & 63;
    const int wave = tid >> 6;
    int tx, ty;
    xcd_swizzle(tx, ty);
    const int m0 = ty * 128;
    const int n0 = tx * 128;
    const int wm = (wave & 1) * 64;
    const int wn = (wave >> 1) * 64;
    const int l15  = lane & 15;
    const int quad = lane >> 4;

    f32x4 acc[4][4];
#pragma unroll
    for (int i = 0; i < 4; ++i)
#pragma unroll
        for (int j = 0; j < 4; ++j) acc[i][j] = (f32x4)0.0f;

    const int crow = tid >> 3;               // staged row within 32-row group
    const int scol = ((tid & 7) ^ (crow & 7)) * 8;   // swizzled source col

    for (int k0 = 0; k0 < K; k0 += 64) {
#pragma unroll
        for (int p = 0; p < 4; ++p) {
            int row = p * 32 + crow;
            const u16* ga = A + (size_t)(m0 + row) * K + k0 + scol;
            char* la = (char*)As + (size_t)(p * 256 + (wave << 6)) * 16;
            __builtin_amdgcn_global_load_lds((const __attribute__((address_space(1))) void*)ga,
                                             (__attribute__((address_space(3))) void*)la, 16, 0, 0);
            const u16* gb = Bm + (size_t)(n0 + row) * K + k0 + scol;
            char* lb = (char*)Bs + (size_t)(p * 256 + (wave << 6)) * 16;
            __builtin_amdgcn_global_load_lds((const __attribute__((address_space(1))) void*)gb,
                                             (__attribute__((address_space(3))) void*)lb, 16, 0, 0);
        }
        __syncthreads();
#pragma unroll
        for (int kk = 0; kk < 64; kk += 32) {
            bf16x8 af[4], bfr[4];
#pragma unroll
            for (int i = 0; i < 4; ++i) {
                int sa = (((kk >> 3) + quad) ^ (l15 & 7)) * 8;   // inverse swizzle
                af[i]  = *(const bf16x8*)&As[(wm + i * 16 + l15) * 64 + sa];
                bfr[i] = *(const bf16x8*)&Bs[(wn + i * 16 + l15) * 64 + sa];
            }
#pragma unroll
            for (int i = 0; i < 4; ++i)
#pragma unroll
                for (int j = 0; j < 4; ++j)
                    acc[i][j] = __builtin_amdgcn_mfma_f32_16x16x32_bf16(af[i], bfr[j], acc[i][j], 0, 0, 0);
        }
        __syncthreads();
    }
#pragma unroll
    for (int i = 0; i < 4; ++i) {
#pragma unroll
        for (int j = 0; j < 4; ++j) {
#pragma unroll
            for (int r = 0; r < 4; ++r) {
                int grow = m0 + wm + i * 16 + quad * 4 + r;
                int gcol = n0 + wn + j * 16 + l15;
                if (OUT_BF16) {
                    ((u16*)Cv)[(size_t)grow * N + gcol] = f2bf(acc[i][j][r]);
                } else {
                    ((float*)Cv)[(size_t)grow * N + gcol] = acc[i][j][r];
                }
            }
        }
    }
}

// One MFMA quadrant (16 MFMAs), Q must be a literal (keeps acc indexing static).
#define MFMA_Q(Q, AF) do {                                                      \
    __builtin_amdgcn_s_setprio(1);                                              \
    _Pragma("unroll")                                                           \
    for (int i_ = 0; i_ < 2; ++i_)                                              \
        _Pragma("unroll")                                                       \
        for (int j_ = 0; j_ < 4; ++j_)                                          \
            _Pragma("unroll")                                                   \
            for (int kk_ = 0; kk_ < 2; ++kk_)                                   \
                acc[(Q) * 2 + i_][j_] = __builtin_amdgcn_mfma_f32_16x16x32_bf16(\
                    AF[i_][kk_], bB[j_][kk_], acc[(Q) * 2 + i_][j_], 0, 0, 0);  \
    __builtin_amdgcn_s_setprio(0); } while (0)

#define SBAR __builtin_amdgcn_s_barrier()
#define SGB  __builtin_amdgcn_sched_barrier(0)

// ---------------- bf16 NT GEMM, 256x256, BK=64, true 4-phase interleave --------
// Port of the m201 8-phase schedule (4 phases/K-tile here): per phase
// {ds_read next-quadrant frags || issue 1 half-tile stage || barrier || 16 MFMA
// || barrier}, vmcnt(6) once per K-tile (3 half-tiles always in flight).
// Quadrant q uses A rows [64q,64q+64) -> regions free progressively; stage
// placement audited against the trailing barrier that closes each region's
// reads. R2-verified involution swizzle throughout.
template<int OUT_BF16>
__global__ __launch_bounds__(512, 2) void gemm_nt_256(const u16* __restrict__ A,
                                                      const u16* __restrict__ Bm,
                                                      void* __restrict__ Cv,
                                                      int M, int N, int K) {
    __shared__ __align__(16) u16 sA[2][256 * 64];   // 64 KiB
    __shared__ __align__(16) u16 sB[2][256 * 64];   // 64 KiB
    const int tid  = threadIdx.x;
    const int lane = tid & 63;
    const int wave = tid >> 6;       // 0..7
    const int wr   = wave >> 2;      // 0..1
    const int wc   = wave & 3;       // 0..3 -> cols [wc*64, +64)
    const int l15  = lane & 15;
    const int quad = lane >> 4;
    int tx, ty;
    xcd_swizzle(tx, ty);
    const int m0 = ty * 256;
    const int n0 = tx * 256;

    f32x4 acc[8][4];
#pragma unroll
    for (int i = 0; i < 8; ++i)
#pragma unroll
        for (int j = 0; j < 4; ++j) acc[i][j] = (f32x4)0.0f;

    // Stage one half-tile (1024 granules of 16B = 2 loads/thread) of A or B.
    // granule g: row=g>>3, LDS col-slot c=g&7 holds source granule c^(row&7).
    auto stageA = [&](int buf, int half, int k0) {
#pragma unroll
        for (int p = 0; p < 2; ++p) {
            const int gbase = half * 1024 + p * 512 + wave * 64;  // wave-uniform
            const int g   = gbase + lane;
            const int row = g >> 3;
            const int sc  = ((g & 7) ^ (row & 7)) * 8;
            const u16* ga = A + (size_t)(m0 + row) * K + k0 + sc;
            __builtin_amdgcn_global_load_lds(
                (const __attribute__((address_space(1))) void*)ga,
                (__attribute__((address_space(3))) void*)((char*)&sA[buf][0] + (size_t)gbase * 16),
                16, 0, 0);
        }
    };
    auto stageB = [&](int buf, int half, int k0) {
#pragma unroll
        for (int p = 0; p < 2; ++p) {
            const int gbase = half * 1024 + p * 512 + wave * 64;
            const int g   = gbase + lane;
            const int row = g >> 3;
            const int sc  = ((g & 7) ^ (row & 7)) * 8;
            const u16* gb = Bm + (size_t)(n0 + row) * K + k0 + sc;
            __builtin_amdgcn_global_load_lds(
                (const __attribute__((address_space(1))) void*)gb,
                (__attribute__((address_space(3))) void*)((char*)&sB[buf][0] + (size_t)gbase * 16),
                16, 0, 0);
        }
    };

    const int NT = K >> 6;
    // Prologue: all of tile 0, then 3 halves of tile 1 (B-hi of T issued in T-1's P0).
    stageB(0, 0, 0); stageA(0, 0, 0); stageA(0, 1, 0); stageB(0, 1, 0);
    if (NT > 1) { stageB(1, 0, 64); stageA(1, 0, 64); stageA(1, 1, 64); }

    for (int T = 0; T < NT; ++T) {
        const int P  = T & 1;
        const int k1 = (T + 1) << 6, k2 = (T + 2) << 6;
        const bool s1 = (T + 1 < NT), s2 = (T + 2 < NT);

        SGB;
        // Gate: newest 3 half-tiles (tile T+1's B-lo/A-h0/A-h1) may stay in
        // flight; everything of tile T is older -> landed. No full drain.
        if (s1) asm volatile("s_waitcnt vmcnt(6)" ::: "memory");
        else    asm volatile("s_waitcnt vmcnt(0)" ::: "memory");
        SGB;
        SBAR;          // collective: buf[P] staged & prior readers done
        SGB;

        bf16x8 bB[4][2], aX[2][2], aY[2][2];
        // ---- P0: read B(8) + A q0,q1 (8); stage T+1's B-hi; MFMA q0
#pragma unroll
        for (int j = 0; j < 4; ++j)
#pragma unroll
            for (int kk = 0; kk < 2; ++kk) {
                int row  = wc * 64 + j * 16 + l15;
                int slot = ((kk * 4 + quad) ^ (l15 & 7)) * 8;
                bB[j][kk] = lds_ld16(&sB[P][row * 64 + slot]);
            }
#pragma unroll
        for (int i = 0; i < 2; ++i)
#pragma unroll
            for (int kk = 0; kk < 2; ++kk) {
                int slot = ((kk * 4 + quad) ^ (l15 & 7)) * 8;
                aX[i][kk] = lds_ld16(&sA[P][(0 * 64 + wr * 32 + i * 16 + l15) * 64 + slot]);
                aY[i][kk] = lds_ld16(&sA[P][(1 * 64 + wr * 32 + i * 16 + l15) * 64 + slot]);
            }
        if (s1) stageB(P ^ 1, 1, k1);
        SGB; SBAR;
        MFMA_Q(0, aX);
        SGB; SBAR;
        // ---- P1: read A q2; stage T+2's B-lo (B[P] reads closed at P0 trail); MFMA q1
#pragma unroll
        for (int i = 0; i < 2; ++i)
#pragma unroll
            for (int kk = 0; kk < 2; ++kk) {
                int slot = ((kk * 4 + quad) ^ (l15 & 7)) * 8;
                aX[i][kk] = lds_ld16(&sA[P][(2 * 64 + wr * 32 + i * 16 + l15) * 64 + slot]);
            }
        if (s2) stageB(P, 0, k2);
        SGB; SBAR;
        MFMA_Q(1, aY);
        SGB; SBAR;
        // ---- P2: read A q3; stage T+2's A-h0 (rows 0-127 closed at P1 trail); MFMA q2
#pragma unroll
        for (int i = 0; i < 2; ++i)
#pragma unroll
            for (int kk = 0; kk < 2; ++kk) {
                int slot = ((kk * 4 + quad) ^ (l15 & 7)) * 8;
                aY[i][kk] = lds_ld16(&sA[P][(3 * 64 + wr * 32 + i * 16 + l15) * 64 + slot]);
            }
        if (s2) stageA(P, 0, k2);
        SGB; SBAR;
        MFMA_Q(2, aX);
        SGB; SBAR;
        // ---- P3: MFMA q3; then (after the barrier that closes q3 reads) stage A-h1
        MFMA_Q(3, aY);
        SGB; SBAR;
        if (s2) stageA(P, 1, k2);
    }

#pragma unroll
    for (int q = 0; q < 4; ++q) {
#pragma unroll
        for (int i = 0; i < 2; ++i) {
#pragma unroll
            for (int j = 0; j < 4; ++j) {
#pragma unroll
                for (int r = 0; r < 4; ++r) {
                    int grow = m0 + q * 64 + wr * 32 + i * 16 + quad * 4 + r;
                    int gcol = n0 + wc * 64 + j * 16 + l15;
                    if (OUT_BF16) {
                        ((u16*)Cv)[(size_t)grow * N + gcol] = f2bf(acc[q * 2 + i][j][r]);
                    } else {
                        ((float*)Cv)[(size_t)grow * N + gcol] = acc[q * 2 + i][j][r];
                    }
                }
            }
        }
    }
}

// ---------------- beta/g epilogue over bg scores [4096 x 128(64 used)] ----------
__global__ __launch_bounds__(256) void bg_epilogue(const float* __restrict__ scores,
                                                   const float* __restrict__ dt_bias,
                                                   const float* __restrict__ A_log,
                                                   float* __restrict__ beta,
                                                   float* __restrict__ g) {
    int i = blockIdx.x * 256 + threadIdx.x;   // 4096*64
    int row = i >> 6, col = i & 63;
    float s = scores[(size_t)row * 128 + col];
    if (col < 32) {
        beta[(size_t)row * 32 + col] = 1.f / (1.f + __expf(-s));
    } else {
        int h = col - 32;
        float aa = s + dt_bias[h];
        float sp = (aa > 20.f) ? aa : log1pf(__expf(aa));
        g[(size_t)row * 32 + h] = -__expf(A_log[h]) * sp;
    }
}

// ---------------- causal depthwise conv (K=4) + silu -> bf16 ----------------
__global__ __launch_bounds__(256) void conv_silu_kernel(const u16* __restrict__ qkv,
                                                        const float* __restrict__ conv_w,
                                                        const float* __restrict__ conv_state,
                                                        const int* __restrict__ input_pos,
                                                        u16* __restrict__ qkvc) {
    const int d   = blockIdx.x * 256 + threadIdx.x;
    const int row = blockIdx.y;
    const int t   = row & (TT - 1);
    const int b   = row >> 11;
    const float keep = (input_pos[0] == 0) ? 0.f : 1.f;
    float4 w = *(const float4*)&conv_w[(size_t)d * 4];
    float acc = 0.f;
#pragma unroll
    for (int j = 0; j < 4; ++j) {
        int u = t + j - 3;
        float v;
        if (u >= 0) v = bf2f(qkv[(size_t)(b * TT + u) * CONV_DIM + d]);
        else        v = keep * conv_state[((size_t)b * CONV_DIM + d) * 4 + (u + 4)];
        acc += (&w.x)[j] * v;
    }
    float s = acc / (1.f + __expf(-acc));
    qkvc[(size_t)row * CONV_DIM + d] = f2bf(s);
}

// ---------------- q/k L2 normalize in place (bf16) ----------------
__global__ __launch_bounds__(256) void qknorm_kernel(u16* __restrict__ qkvc) {
    const int gid  = blockIdx.x * 4 + (threadIdx.x >> 6);
    const int lane = threadIdx.x & 63;
    const int row  = gid >> 5;
    const int h    = gid & 31;
    u16* p = qkvc + (size_t)row * CONV_DIM + h * 128;
    ushort2 vb = *(ushort2*)&p[lane * 2];
    float v0 = bf2f(vb.x), v1 = bf2f(vb.y);
    float ss = v0 * v0 + v1 * v1;
#pragma unroll
    for (int off = 32; off; off >>= 1) ss += __shfl_xor(ss, off);
    float scale = 1.f / fmaxf(sqrtf(ss), 1e-12f);
    ushort2 r;
    r.x = f2bf(v0 * scale);
    r.y = f2bf(v1 * scale);
    *(ushort2*)&p[lane * 2] = r;
}

// ---------------- K1: per-chunk gate prefix (wave scan, CH=64) ----------------
__global__ __launch_bounds__(64) void gates_kernel(const float* __restrict__ g,
                                                   const float* __restrict__ beta_,
                                                   float* __restrict__ gcum,
                                                   float* __restrict__ qsb,
                                                   float* __restrict__ wkb,
                                                   float* __restrict__ dLb) {
    const int bh = blockIdx.x, c = blockIdx.y;
    const int b = bh >> 5, h = bh & 31;
    const int t = threadIdx.x;
    const int row = b * TT + c * CH + t;
    float G = g[(size_t)row * 32 + h];
#pragma unroll
    for (int off = 1; off < 64; off <<= 1) {
        float x = __shfl_up(G, off);
        if (t >= off) G += x;
    }
    float GL = __shfl(G, 63);
    int oidx = bh * TT + c * CH + t;
    gcum[oidx] = G;
    qsb[oidx] = __expf(G);
    wkb[oidx] = __expf(GL - G) * beta_[(size_t)row * 32 + h];
    if (t == 0) dLb[bh * NCHUNK + c] = __expf(GL);
}

// ---------------- kT transpose: qkvc k-section -> kT[B][NK][DK][T] ----------------
__global__ __launch_bounds__(256) void ktrans_kernel(const u16* __restrict__ qkvc,
                                                     u16* __restrict__ kT) {
    const int id = blockIdx.x;
    const int tt = id & 31, dkh = (id >> 5) & 1, hk = (id >> 6) & 15, b = id >> 10;
    const int t0 = tt * 64, dk0 = dkh * 64;
    __shared__ __align__(16) u16 tile[64 * 68];
#pragma unroll
    for (int it = 0; it < 2; ++it) {
        int idx = it * 256 + threadIdx.x;
        int tl = idx >> 3, c8 = (idx & 7) * 8;
        uint4 v = *(const uint4*)&qkvc[(size_t)(b * TT + t0 + tl) * CONV_DIM + KEY_DIM + hk * 128 + dk0 + c8];
        lds_st8(&tile[tl * 68 + c8], v);
    }
    __syncthreads();
#pragma unroll
    for (int it = 0; it < 2; ++it) {
        int idx = it * 256 + threadIdx.x;
        int dkl = idx >> 3, t8 = (idx & 7) * 8;
        unsigned w[4];
#pragma unroll
        for (int p = 0; p < 4; ++p) {
            unsigned lo = tile[(t8 + 2 * p) * 68 + dkl];
            unsigned hi = tile[(t8 + 2 * p + 1) * 68 + dkl];
            w[p] = lo | (hi << 16);
        }
        *(uint4*)&kT[((size_t)((b * 16 + hk) * 128 + dk0 + dkl)) * TT + t0 + t8] =
            make_uint4(w[0], w[1], w[2], w[3]);
    }
}

// ---------------- K2: chunk state pass + inter output (MFMA) ----------------
__global__ __launch_bounds__(256) void chunk_state_kernel(const u16* __restrict__ qkvc,
                                                          const u16* __restrict__ kT,
                                                          const float* __restrict__ qsb,
                                                          const float* __restrict__ wkb,
                                                          const float* __restrict__ dLb,
                                                          const float* __restrict__ rec_state,
                                                          const int* __restrict__ input_pos,
                                                          u16* __restrict__ o) {
    const int b = blockIdx.x, h = blockIdx.y, dvs = blockIdx.z;
    const int tid = threadIdx.x, lane = tid & 63, wave = tid >> 6;
    const int l15 = lane & 15, quad = lane >> 4;
    const int hq = h >> 1, bh = b * 32 + h;
    const float keep = (input_pos[0] == 0) ? 0.f : 1.f;

    __shared__ __align__(16) u16 sQ[64 * 132];
    __shared__ __align__(16) u16 sKT[128 * 68];
    __shared__ __align__(16) u16 sR[32 * 132];
    __shared__ float sQS[64];

    f32x4 st[2][2];
#pragma unroll
    for (int i = 0; i < 2; ++i)
#pragma unroll
        for (int j = 0; j < 2; ++j)
#pragma unroll
            for (int r = 0; r < 4; ++r) {
                int dv = dvs * 32 + i * 16 + quad * 4 + r;
                int dk = wave * 32 + j * 16 + l15;
                st[i][j][r] = keep * rec_state[((size_t)(bh * 128 + dk)) * 128 + dv];
            }

    for (int c = 0; c < NCHUNK; ++c) {
        const int t0 = c * CH;
#pragma unroll
        for (int i = 0; i < 2; ++i)
#pragma unroll
            for (int j = 0; j < 2; ++j)
#pragma unroll
                for (int r = 0; r < 4; ++r)
                    sR[(i * 16 + quad * 4 + r) * 132 + wave * 32 + j * 16 + l15] = f2bf(st[i][j][r]);
#pragma unroll
        for (int it = 0; it < 4; ++it) {
            int idx = it * 256 + tid;
            int t = idx >> 4, c8 = (idx & 15) * 8;
            uint4 v = *(const uint4*)&qkvc[(size_t)(b * TT + t0 + t) * CONV_DIM + hq * 128 + c8];
            lds_st8(&sQ[t * 132 + c8], v);
        }
        if (tid < 64) sQS[tid] = qsb[bh * TT + t0 + tid];
        __syncthreads();
        {
            f32x4 ao[2] = {(f32x4)0.0f, (f32x4)0.0f};
#pragma unroll
            for (int kk = 0; kk < 4; ++kk) {
                bf16x8 af = lds_ld8(&sQ[(wave * 16 + l15) * 132 + kk * 32 + quad * 8]);
                bf16x8 b0 = lds_ld8(&sR[(l15) * 132 + kk * 32 + quad * 8]);
                bf16x8 b1 = lds_ld8(&sR[(16 + l15) * 132 + kk * 32 + quad * 8]);
                ao[0] = __builtin_amdgcn_mfma_f32_16x16x32_bf16(af, b0, ao[0], 0, 0, 0);
                ao[1] = __builtin_amdgcn_mfma_f32_16x16x32_bf16(af, b1, ao[1], 0, 0, 0);
            }
#pragma unroll
            for (int j = 0; j < 2; ++j)
#pragma unroll
                for (int r = 0; r < 4; ++r) {
                    int t = wave * 16 + quad * 4 + r;
                    int dv = dvs * 32 + j * 16 + l15;
                    o[((size_t)(b * TT + t0 + t) * 32 + h) * 128 + dv] = f2bf(ao[j][r] * sQS[t]);
                }
        }
        __syncthreads();
#pragma unroll
        for (int it = 0; it < 4; ++it) {
            int idx = it * 256 + tid;
            int dk = idx >> 3, t8 = (idx & 7) * 8;
            uint4 v = *(const uint4*)&kT[((size_t)((b * 16 + hq) * 128 + dk)) * TT + t0 + t8];
            lds_st8(&sKT[dk * 68 + t8], v);
        }
        {
            int t = tid >> 2, dvo = (tid & 3) * 8;
            float w = wkb[bh * TT + t0 + t];
            BF8 v;
            v.u4 = *(const uint4*)&qkvc[(size_t)(b * TT + t0 + t) * CONV_DIM + 2 * KEY_DIM + h * 128 + dvs * 32 + dvo];
#pragma unroll
            for (int u = 0; u < 8; ++u)
                sR[(dvo + u) * 68 + t] = f2bf(bf2f(v.s[u]) * w);
        }
        __syncthreads();
        {
            float d = dLb[bh * NCHUNK + c];
#pragma unroll
            for (int i = 0; i < 2; ++i)
#pragma unroll
                for (int j = 0; j < 2; ++j)
#pragma unroll
                    for (int r = 0; r < 4; ++r) st[i][j][r] *= d;
#pragma unroll
            for (int kk = 0; kk < 2; ++kk) {
                bf16x8 af[2], bfv[2];
#pragma unroll
                for (int i = 0; i < 2; ++i)
                    af[i] = lds_ld8(&sR[(i * 16 + l15) * 68 + kk * 32 + quad * 8]);
#pragma unroll
                for (int j = 0; j < 2; ++j)
                    bfv[j] = lds_ld8(&sKT[(wave * 32 + j * 16 + l15) * 68 + kk * 32 + quad * 8]);
#pragma unroll
                for (int i = 0; i < 2; ++i)
#pragma unroll
                    for (int j = 0; j < 2; ++j)
                        st[i][j] = __builtin_amdgcn_mfma_f32_16x16x32_bf16(af[i], bfv[j], st[i][j], 0, 0, 0);
            }
        }
        __syncthreads();
    }
}

// ---------------- K3: intra-chunk causal attention (MFMA), adds into o ----------------
__global__ __launch_bounds__(256) void chunk_intra_kernel(const u16* __restrict__ qkvc,
                                                          const float* __restrict__ gcum,
                                                          const float* __restrict__ beta_,
                                                          u16* __restrict__ o) {
    const int b = blockIdx.x, h = blockIdx.y, c = blockIdx.z;
    const int tid = threadIdx.x, lane = tid & 63, wave = tid >> 6;
    const int l15 = lane & 15, quad = lane >> 4;
    const int hq = h >> 1, bh = b * 32 + h;
    const int t0 = c * CH;

    __shared__ __align__(16) u16 sQ[64 * 132];
    __shared__ __align__(16) u16 sK[64 * 132];
    __shared__ __align__(16) u16 sVT[128 * 68];
    __shared__ float sG[64];
    __shared__ float sB[64];

#pragma unroll
    for (int it = 0; it < 4; ++it) {
        int idx = it * 256 + tid;
        int t = idx >> 4, c8 = (idx & 15) * 8;
        size_t rbase = (size_t)(b * TT + t0 + t) * CONV_DIM;
        lds_st8(&sQ[t * 132 + c8], *(const uint4*)&qkvc[rbase + hq * 128 + c8]);
        lds_st8(&sK[t * 132 + c8], *(const uint4*)&qkvc[rbase + KEY_DIM + hq * 128 + c8]);
    }
    if (tid < 64) {
        sG[tid] = gcum[bh * TT + t0 + tid];
        sB[tid] = beta_[(size_t)(b * TT + t0 + tid) * 32 + h];
    }
    __syncthreads();
    const int wm = (wave & 1) * 32, wn = (wave >> 1) * 32;
    f32x4 acc[2][2];
#pragma unroll
    for (int i = 0; i < 2; ++i)
#pragma unroll
        for (int j = 0; j < 2; ++j) acc[i][j] = (f32x4)0.0f;
#pragma unroll
    for (int kk = 0; kk < 4; ++kk) {
        bf16x8 af[2], bfv[2];
#pragma unroll
        for (int i = 0; i < 2; ++i) {
            af[i]  = lds_ld8(&sQ[(wm + i * 16 + l15) * 132 + kk * 32 + quad * 8]);
            bfv[i] = lds_ld8(&sK[(wn + i * 16 + l15) * 132 + kk * 32 + quad * 8]);
        }
#pragma unroll
        for (int i = 0; i < 2; ++i)
#pragma unroll
            for (int j = 0; j < 2; ++j)
                acc[i][j] = __builtin_amdgcn_mfma_f32_16x16x32_bf16(af[i], bfv[j], acc[i][j], 0, 0, 0);
    }
    __syncthreads();
#pragma unroll
    for (int i = 0; i < 2; ++i)
#pragma unroll
        for (int j = 0; j < 2; ++j)
#pragma unroll
            for (int r = 0; r < 4; ++r) {
                int t = wm + i * 16 + quad * 4 + r;
                int s = wn + j * 16 + l15;
                float av = 0.f;
                if (s <= t) av = __expf(sG[t] - sG[s]) * sB[s] * acc[i][j][r];
                ((u16*)sQ)[t * 68 + s] = f2bf(av);
            }
#pragma unroll
    for (int it = 0; it < 4; ++it) {
        int idx = it * 256 + tid;
        int t = idx >> 4, c8 = (idx & 15) * 8;
        lds_st8(&sK[t * 132 + c8],
                *(const uint4*)&qkvc[(size_t)(b * TT + t0 + t) * CONV_DIM + 2 * KEY_DIM + h * 128 + c8]);
    }
    __syncthreads();
    {
        int dv = (wave & 1) * 64 + lane;
        int tb = (wave >> 1) * 32;
#pragma unroll
        for (int tc = 0; tc < 4; ++tc) {
            int t8 = tb + tc * 8;
            unsigned w[4];
#pragma unroll
            for (int p = 0; p < 4; ++p) {
                unsigned lo = sK[(t8 + 2 * p) * 132 + dv];
                unsigned hi = sK[(t8 + 2 * p + 1) * 132 + dv];
                w[p] = lo | (hi << 16);
            }
            lds_st8(&sVT[dv * 68 + t8], make_uint4(w[0], w[1], w[2], w[3]));
        }
    }
    __syncthreads();
    const int wm2 = (wave & 1) * 32, wn2 = (wave >> 1) * 64;
    f32x4 oacc[2][4];
#pragma unroll
    for (int i = 0; i < 2; ++i)
#pragma unroll
        for (int j = 0; j < 4; ++j) oacc[i][j] = (f32x4)0.0f;
#pragma unroll
    for (int kk = 0; kk < 2; ++kk) {
        bf16x8 af[2], bfv[4];
#pragma unroll
        for (int i = 0; i < 2; ++i)
            af[i] = lds_ld8(&((u16*)sQ)[(wm2 + i * 16 + l15) * 68 + kk * 32 + quad * 8]);
#pragma unroll
        for (int j = 0; j < 4; ++j)
            bfv[j] = lds_ld8(&sVT[(wn2 + j * 16 + l15) * 68 + kk * 32 + quad * 8]);
#pragma unroll
        for (int i = 0; i < 2; ++i)
#pragma unroll
            for (int j = 0; j < 4; ++j)
                oacc[i][j] = __builtin_amdgcn_mfma_f32_16x16x32_bf16(af[i], bfv[j], oacc[i][j], 0, 0, 0);
    }
#pragma unroll
    for (int i = 0; i < 2; ++i)
#pragma unroll
        for (int j = 0; j < 4; ++j)
#pragma unroll
            for (int r = 0; r < 4; ++r) {
                int t = wm2 + i * 16 + quad * 4 + r;
                int dv = wn2 + j * 16 + l15;
                size_t addr = ((size_t)(b * TT + t0 + t) * 32 + h) * 128 + dv;
                o[addr] = f2bf(oacc[i][j][r] + bf2f(o[addr]));
            }
}

// ---------------- gated RMSNorm: o *= silu(z); rmsnorm; -> bf16 ----------------
__global__ __launch_bounds__(256) void gnorm_kernel(const u16* __restrict__ o,
                                                    const u16* __restrict__ zb,
                                                    const float* __restrict__ norm_w,
                                                    u16* __restrict__ ob) {
    const int gid  = blockIdx.x * 4 + (threadIdx.x >> 6);
    const int lane = threadIdx.x & 63;
    const int row  = gid >> 5;
    const int h    = gid & 31;
    const size_t base = ((size_t)row * NVH + h) * DVD;
    ushort2 oraw = *(const ushort2*)&o[base + lane * 2];
    float o0 = bf2f(oraw.x), o1 = bf2f(oraw.y);
    float z0 = bf2f(zb[base + lane * 2]);
    float z1 = bf2f(zb[base + lane * 2 + 1]);
    o0 *= z0 / (1.f + __expf(-z0));
    o1 *= z1 / (1.f + __expf(-z1));
    float ss = o0 * o0 + o1 * o1;
#pragma unroll
    for (int off = 32; off; off >>= 1) ss += __shfl_xor(ss, off);
    float scale = rsqrtf(ss * (1.f / 128.f) + 1e-6f);
    float w0 = norm_w[lane * 2], w1 = norm_w[lane * 2 + 1];
    ushort2 r;
    r.x = f2bf(o0 * scale * w0);
    r.y = f2bf(o1 * scale * w1);
    *(ushort2*)&ob[base + lane * 2] = r;
}

extern "C" void kernel_launch(void* const* d_in, const int* in_sizes, int n_in,
                              void* d_out, int out_size, void* d_ws, size_t ws_size,
                              hipStream_t stream) {
    const float* x         = (const float*)d_in[0];
    const int*   input_pos = (const int*)d_in[1];
    const float* W_qkv     = (const float*)d_in[2];
    const float* W_z       = (const float*)d_in[3];
    const float* W_b       = (const float*)d_in[4];
    const float* W_a       = (const float*)d_in[5];
    const float* conv_w    = (const float*)d_in[6];
    const float* dt_bias   = (const float*)d_in[7];
    const float* A_log     = (const float*)d_in[8];
    const float* norm_w    = (const float*)d_in[9];
    const float* W_out     = (const float*)d_in[10];
    const float* conv_state = (const float*)d_in[11];
    const float* rec_state  = (const float*)d_in[12];
    float* out = (float*)d_out;

    const size_t REQUIRED = 168820736;   // 161 MiB
    if (ws_size < REQUIRED) {
        float mib = (float)((double)ws_size / 1048576.0);
        fill_kernel<<<(out_size + 255) / 256, 256, 0, stream>>>(out, mib, out_size);
        return;
    }

    const size_t MI = 1048576;
    char* ws = (char*)d_ws;
    u16* xb    = (u16*)(ws);
    u16* wqkvb = (u16*)(ws + 16 * MI);
    u16* wzb   = (u16*)(ws + 48 * MI);
    u16* wbab  = (u16*)(ws + 16 * MI);      // 128x2048 bf16, alias dead wqkvb
    float* bgs = (float*)(ws + 17 * MI);    // 4096x128 fp32 scores
    u16* qkvc  = (u16*)(ws);
    u16* ob    = (u16*)(ws);
    u16* woutb = (u16*)(ws + 32 * MI);
    u16* zb    = (u16*)(ws + 64 * MI);
    u16* qkvb  = (u16*)(ws + 96 * MI);
    u16* o     = (u16*)(ws + 96 * MI);
    u16* kT    = (u16*)(ws + 128 * MI);
    float* gcum = (float*)(ws + 144 * MI);
    float* qsb  = (float*)(ws + 144 * MI + 524288);
    float* wkb  = (float*)(ws + 145 * MI);
    float* dLb  = (float*)(ws + 145 * MI + 524288);
    float* beta = (float*)(ws + 160 * MI);
    float* g    = (float*)(ws + 160 * MI + 524288);

    // 1. casts
    cast_kernel<<<8192,  256, 0, stream>>>(x,     xb,    2097152);
    cast_kernel<<<16384, 256, 0, stream>>>(W_qkv, wqkvb, 4194304);
    cast_kernel<<<8192,  256, 0, stream>>>(W_z,   wzb,   2097152);

    // 2. big projections: 256x256 4-phase interleaved pipeline
    gemm_nt_256<1><<<dim3(32, 16), 512, 0, stream>>>(xb, wqkvb, qkvb, MROWS, CONV_DIM, CDIM);
    gemm_nt_256<1><<<dim3(16, 16), 512, 0, stream>>>(xb, wzb,   zb,   MROWS, VAL_DIM,  CDIM);

    // 3. beta/g via MFMA GEMM (into dead wqkvb region; before conv clobbers xb)
    cast_kernel<<<256, 256, 0, stream>>>(W_b, wbab, 16384);
    cast_kernel<<<256, 256, 0, stream>>>(W_a, wbab + 65536, 16384);
    hipMemsetAsync(wbab + 131072, 0, 131072 * sizeof(u16), stream);   // pad rows 64..127
    gemm_nt<0><<<dim3(1, 32), 256, 0, stream>>>(xb, wbab, bgs, MROWS, 128, CDIM);
    bg_epilogue<<<1024, 256, 0, stream>>>(bgs, dt_bias, A_log, beta, g);

    // 4. conv + silu (clobbers [0,64Mi)), q/k norm
    conv_silu_kernel<<<dim3(32, 4096), 256, 0, stream>>>(qkvb, conv_w, conv_state, input_pos, qkvc);
    qknorm_kernel<<<32768, 256, 0, stream>>>(qkvc);

    // 5. chunked recurrence
    gates_kernel<<<dim3(64, NCHUNK), 64, 0, stream>>>(g, beta, gcum, qsb, wkb, dLb);
    ktrans_kernel<<<2048, 256, 0, stream>>>(qkvc, kT);
    chunk_state_kernel<<<dim3(BB, NVH, 4), 256, 0, stream>>>(qkvc, kT, qsb, wkb, dLb,
                                                             rec_state, input_pos, o);
    chunk_intra_kernel<<<dim3(BB, NVH, NCHUNK), 256, 0, stream>>>(qkvc, gcum, beta, o);

    // 6. W_out cast (into dead qkvc region) + gated RMSNorm
    cast_kernel<<<8192, 256, 0, stream>>>(W_out, woutb, 2097152);
    gnorm_kernel<<<32768, 256, 0, stream>>>(o, zb, norm_w, ob);

    // 7. output projection (fp32 out; N=2048, 128-tile kernel, conflict-free)
    gemm_nt<0><<<dim3(16, 32), 256, 0, stream>>>(ob, woutb, out, MROWS, CDIM, VAL_DIM);
}

// Round 8
// 747.820 us; speedup vs baseline: 1.0619x; 1.0193x over previous
//
#include <hip/hip_runtime.h>
#include <hip/hip_bf16.h>
#include <math.h>

// Problem constants
#define NKH 16
#define NVH 32
#define DKD 128
#define DVD 128
#define CDIM 2048
#define KEY_DIM 2048   // NK*DK
#define VAL_DIM 4096   // NV*DV
#define CONV_DIM 8192  // 2*KEY_DIM+VAL_DIM
#define BB 2
#define TT 2048
#define MROWS 4096     // B*T
#define CH 64          // recurrence chunk length
#define NCHUNK 32      // TT/CH

typedef unsigned short u16;
typedef __bf16 bf16x8 __attribute__((ext_vector_type(8)));
typedef float f32x4 __attribute__((ext_vector_type(4)));

__device__ __forceinline__ u16 f2bf(float f) {
    union { float f; unsigned u; } a; a.f = f;
    unsigned u = a.u;
    u += 0x7fffu + ((u >> 16) & 1u);
    return (u16)(u >> 16);
}
__device__ __forceinline__ float bf2f(u16 h) {
    union { unsigned u; float f; } a; a.u = ((unsigned)h) << 16;
    return a.f;
}
union BF8 { bf16x8 v; uint2 u2[2]; uint4 u4; u16 s[8]; };
__device__ __forceinline__ bf16x8 lds_ld8(const u16* p) {
    BF8 t; t.u2[0] = *(const uint2*)p; t.u2[1] = *(const uint2*)(p + 4); return t.v;
}
__device__ __forceinline__ bf16x8 lds_ld16(const u16* p) {   // 16B-aligned
    BF8 t; t.u4 = *(const uint4*)p; return t.v;
}
__device__ __forceinline__ void lds_st8(u16* p, uint4 v) {
    *(uint2*)p = make_uint2(v.x, v.y); *(uint2*)(p + 4) = make_uint2(v.z, v.w);
}

// XCD-aware bijective swizzle (neutral measured, harmless)
__device__ __forceinline__ void xcd_swizzle(int& tx, int& ty) {
    const int nx = gridDim.x, ny = gridDim.y;
    const int b  = blockIdx.x + nx * blockIdx.y;
    const int nb = nx * ny;
    if (nx >= 8 && (nx & 7) == 0 && (nb & 255) == 0) {
        const int rnd  = b >> 8;
        const int idx  = b & 255;
        const int xcd  = idx & 7;
        const int slot = idx >> 3;
        const int RX   = nx >> 3;
        const int rx   = xcd & (RX - 1);
        const int ry   = xcd >> __popc(RX - 1);
        tx = rx * 8 + (slot & 7);
        ty = rnd * (256 / nx) + ry * 4 + (slot >> 3);
    } else {
        tx = blockIdx.x; ty = blockIdx.y;
    }
}

// ---------------- diagnostic fill (used only if ws_size too small) -------------
__global__ __launch_bounds__(256) void fill_kernel(float* __restrict__ p, float v, int n) {
    int i = blockIdx.x * 256 + threadIdx.x;
    if (i < n) p[i] = v;
}

// ---------------- cast fp32 -> bf16 (x4 vectorized) ----------------
__global__ __launch_bounds__(256) void cast_kernel(const float* __restrict__ src,
                                                   u16* __restrict__ dst, int n4) {
    int i = blockIdx.x * 256 + threadIdx.x;
    if (i >= n4) return;
    float4 v = ((const float4*)src)[i];
    ushort4 r;
    r.x = f2bf(v.x); r.y = f2bf(v.y); r.z = f2bf(v.z); r.w = f2bf(v.w);
    ((ushort4*)dst)[i] = r;
}

// ---------------- bf16 NT GEMM: C[M,N] = A[M,K] * B[N,K]^T (m97 structure) ------
// 128^2 tile, T2 involution swizzle (R5-verified: removed 5e7 bank conflicts).
// Used for the beta/g GEMM (N=128) and the out-projection (N=2048).
template<int OUT_BF16>
__global__ __launch_bounds__(256) void gemm_nt(const u16* __restrict__ A,
                                               const u16* __restrict__ Bm,
                                               void* __restrict__ Cv,
                                               int M, int N, int K) {
    __shared__ __align__(16) u16 As[128 * 64];
    __shared__ __align__(16) u16 Bs[128 * 64];
    const int tid  = threadIdx.x;
    const int lane = tid & 63;
    const int wave = tid >> 6;
    int tx, ty;
    xcd_swizzle(tx, ty);
    const int m0 = ty * 128;
    const int n0 = tx * 128;
    const int wm = (wave & 1) * 64;
    const int wn = (wave >> 1) * 64;
    const int l15  = lane & 15;
    const int quad = lane >> 4;

    f32x4 acc[4][4];
#pragma unroll
    for (int i = 0; i < 4; ++i)
#pragma unroll
        for (int j = 0; j < 4; ++j) acc[i][j] = (f32x4)0.0f;

    const int crow = tid >> 3;               // staged row within 32-row group
    const int scol = ((tid & 7) ^ (crow & 7)) * 8;   // swizzled source col

    for (int k0 = 0; k0 < K; k0 += 64) {
#pragma unroll
        for (int p = 0; p < 4; ++p) {
            int row = p * 32 + crow;
            const u16* ga = A + (size_t)(m0 + row) * K + k0 + scol;
            char* la = (char*)As + (size_t)(p * 256 + (wave << 6)) * 16;
            __builtin_amdgcn_global_load_lds((const __attribute__((address_space(1))) void*)ga,
                                             (__attribute__((address_space(3))) void*)la, 16, 0, 0);
            const u16* gb = Bm + (size_t)(n0 + row) * K + k0 + scol;
            char* lb = (char*)Bs + (size_t)(p * 256 + (wave << 6)) * 16;
            __builtin_amdgcn_global_load_lds((const __attribute__((address_space(1))) void*)gb,
                                             (__attribute__((address_space(3))) void*)lb, 16, 0, 0);
        }
        __syncthreads();
#pragma unroll
        for (int kk = 0; kk < 64; kk += 32) {
            bf16x8 af[4], bfr[4];
#pragma unroll
            for (int i = 0; i < 4; ++i) {
                int sa = (((kk >> 3) + quad) ^ (l15 & 7)) * 8;   // inverse swizzle
                af[i]  = *(const bf16x8*)&As[(wm + i * 16 + l15) * 64 + sa];
                bfr[i] = *(const bf16x8*)&Bs[(wn + i * 16 + l15) * 64 + sa];
            }
#pragma unroll
            for (int i = 0; i < 4; ++i)
#pragma unroll
                for (int j = 0; j < 4; ++j)
                    acc[i][j] = __builtin_amdgcn_mfma_f32_16x16x32_bf16(af[i], bfr[j], acc[i][j], 0, 0, 0);
        }
        __syncthreads();
    }
#pragma unroll
    for (int i = 0; i < 4; ++i) {
#pragma unroll
        for (int j = 0; j < 4; ++j) {
#pragma unroll
            for (int r = 0; r < 4; ++r) {
                int grow = m0 + wm + i * 16 + quad * 4 + r;
                int gcol = n0 + wn + j * 16 + l15;
                if (OUT_BF16) {
                    ((u16*)Cv)[(size_t)grow * N + gcol] = f2bf(acc[i][j][r]);
                } else {
                    ((float*)Cv)[(size_t)grow * N + gcol] = acc[i][j][r];
                }
            }
        }
    }
}

// ---------------- bf16 NT GEMM, 256x256 tile, 8 waves, counted-vmcnt pipeline ---
// R2-MEASURED WINNER (152 us on qkv, MfmaUtil 38, 0 bank conflicts). Restored
// verbatim after R3/R5/R7 structural variants all measured slower (154/173/167).
// T2 swizzle: linear wave-uniform gload_lds dest + pre-swizzled global source +
// XOR-swizzled ds_read. Prefetch distance 1 tile, vmcnt(8) never 0 in the loop.
template<int OUT_BF16>
__global__ __launch_bounds__(512, 2) void gemm_nt_256(const u16* __restrict__ A,
                                                      const u16* __restrict__ Bm,
                                                      void* __restrict__ Cv,
                                                      int M, int N, int K) {
    __shared__ __align__(16) u16 sA[2][256 * 64];   // 64 KiB
    __shared__ __align__(16) u16 sB[2][256 * 64];   // 64 KiB
    const int tid  = threadIdx.x;
    const int lane = tid & 63;
    const int wave = tid >> 6;       // 0..7
    const int wr   = wave >> 2;      // 0..1  -> rows [wr*128, +128)
    const int wc   = wave & 3;       // 0..3  -> cols [wc*64,  +64)
    const int l15  = lane & 15;
    const int quad = lane >> 4;
    int tx, ty;
    xcd_swizzle(tx, ty);
    const int m0 = ty * 256;
    const int n0 = tx * 256;

    f32x4 acc[8][4];
#pragma unroll
    for (int i = 0; i < 8; ++i)
#pragma unroll
        for (int j = 0; j < 4; ++j) acc[i][j] = (f32x4)0.0f;

    // staging: 2048 granules of 16B per matrix; wave w, pass p owns granules
    // [p*512 + w*64, +64) written by HW at uniform base + lane*16.
    // Lane's granule g: row = g>>3, source column-granule sc = (g&7)^(row&7)
    // (involution; ds_read applies the same XOR to recover the true layout).
    auto stage = [&](int buf, int kk0) {
#pragma unroll
        for (int p = 0; p < 4; ++p) {
            const int gbase = p * 512 + wave * 64;       // wave-uniform
            const int g   = gbase + lane;                // this lane's granule
            const int row = g >> 3;                      // 0..255
            const int sc  = (g & 7) ^ (row & 7);         // swizzled source granule
            const u16* ga = A + (size_t)(m0 + row) * K + kk0 + sc * 8;
            __builtin_amdgcn_global_load_lds(
                (const __attribute__((address_space(1))) void*)ga,
                (__attribute__((address_space(3))) void*)((char*)&sA[buf][0] + (size_t)gbase * 16),
                16, 0, 0);
            const u16* gb = Bm + (size_t)(n0 + row) * K + kk0 + sc * 8;
            __builtin_amdgcn_global_load_lds(
                (const __attribute__((address_space(1))) void*)gb,
                (__attribute__((address_space(3))) void*)((char*)&sB[buf][0] + (size_t)gbase * 16),
                16, 0, 0);
        }
    };

    const int NT = K >> 6;
    stage(0, 0);                                  // prologue: tile 0 -> buf 0

    for (int T = 0; T < NT; ++T) {
        const int P = T & 1;
        __builtin_amdgcn_sched_barrier(0);        // prefetch must not hoist above prior barrier
        if (T + 1 < NT) {
            stage(P ^ 1, (T + 1) << 6);           // issue next tile first (stays in flight)
            asm volatile("s_waitcnt vmcnt(8)" ::: "memory");   // tile T landed; T+1's 8 in flight
        } else {
            asm volatile("s_waitcnt vmcnt(0)" ::: "memory");   // epilogue drain
        }
        __builtin_amdgcn_s_barrier();
        __builtin_amdgcn_sched_barrier(0);        // no ds_read hoists above the barrier
#pragma unroll
        for (int kk = 0; kk < 2; ++kk) {
            bf16x8 af[8], bfv[4];
#pragma unroll
            for (int i = 0; i < 8; ++i) {
                int row = wr * 128 + i * 16 + l15;
                int slot = ((kk * 4 + quad) ^ (l15 & 7)) * 8;   // row&7 == l15&7
                af[i] = lds_ld16(&sA[P][row * 64 + slot]);
            }
#pragma unroll
            for (int j = 0; j < 4; ++j) {
                int row = wc * 64 + j * 16 + l15;
                int slot = ((kk * 4 + quad) ^ (l15 & 7)) * 8;
                bfv[j] = lds_ld16(&sB[P][row * 64 + slot]);
            }
#pragma unroll
            for (int i = 0; i < 8; ++i)
#pragma unroll
                for (int j = 0; j < 4; ++j)
                    acc[i][j] = __builtin_amdgcn_mfma_f32_16x16x32_bf16(af[i], bfv[j], acc[i][j], 0, 0, 0);
        }
        __builtin_amdgcn_sched_barrier(0);        // no ds_read sinks below the barrier
        __builtin_amdgcn_s_barrier();             // close reads of buf[P] before next STAGE into it
    }

#pragma unroll
    for (int i = 0; i < 8; ++i) {
#pragma unroll
        for (int j = 0; j < 4; ++j) {
#pragma unroll
            for (int r = 0; r < 4; ++r) {
                int grow = m0 + wr * 128 + i * 16 + quad * 4 + r;
                int gcol = n0 + wc * 64 + j * 16 + l15;
                if (OUT_BF16) {
                    ((u16*)Cv)[(size_t)grow * N + gcol] = f2bf(acc[i][j][r]);
                } else {
                    ((float*)Cv)[(size_t)grow * N + gcol] = acc[i][j][r];
                }
            }
        }
    }
}

// ---------------- beta/g epilogue over bg scores [4096 x 128(64 used)] ----------
__global__ __launch_bounds__(256) void bg_epilogue(const float* __restrict__ scores,
                                                   const float* __restrict__ dt_bias,
                                                   const float* __restrict__ A_log,
                                                   float* __restrict__ beta,
                                                   float* __restrict__ g) {
    int i = blockIdx.x * 256 + threadIdx.x;   // 4096*64
    int row = i >> 6, col = i & 63;
    float s = scores[(size_t)row * 128 + col];
    if (col < 32) {
        beta[(size_t)row * 32 + col] = 1.f / (1.f + __expf(-s));
    } else {
        int h = col - 32;
        float aa = s + dt_bias[h];
        float sp = (aa > 20.f) ? aa : log1pf(__expf(aa));
        g[(size_t)row * 32 + h] = -__expf(A_log[h]) * sp;
    }
}

// ---------------- causal depthwise conv (K=4) + silu -> bf16, 8-wide -----------
// Vectorized (G13): each thread owns 8 channels; row reads are uint4 (16 B/lane),
// weights are float4 (L2-resident), store is uint4. Replaces 4 scalar bf16
// loads/thread over a ~320 MB stream.
__global__ __launch_bounds__(256) void conv_silu_kernel(const u16* __restrict__ qkv,
                                                        const float* __restrict__ conv_w,
                                                        const float* __restrict__ conv_state,
                                                        const int* __restrict__ input_pos,
                                                        u16* __restrict__ qkvc) {
    const int d0  = (blockIdx.x * 256 + threadIdx.x) * 8;   // grid.x = 4 -> 8192 channels
    const int row = blockIdx.y;
    const int t   = row & (TT - 1);
    const int b   = row >> 11;
    const float keep = (input_pos[0] == 0) ? 0.f : 1.f;

    float w[8][4];
#pragma unroll
    for (int c = 0; c < 8; ++c) {
        float4 wv = *(const float4*)&conv_w[(size_t)(d0 + c) * 4];
        w[c][0] = wv.x; w[c][1] = wv.y; w[c][2] = wv.z; w[c][3] = wv.w;
    }
    float acc[8];
#pragma unroll
    for (int c = 0; c < 8; ++c) acc[c] = 0.f;
#pragma unroll
    for (int j = 0; j < 4; ++j) {
        int u = t + j - 3;
        if (u >= 0) {                                     // wave-uniform branch
            BF8 v;
            v.u4 = *(const uint4*)&qkv[(size_t)(b * TT + u) * CONV_DIM + d0];
#pragma unroll
            for (int c = 0; c < 8; ++c) acc[c] += w[c][j] * bf2f(v.s[c]);
        } else {
#pragma unroll
            for (int c = 0; c < 8; ++c)
                acc[c] += w[c][j] * keep *
                          conv_state[((size_t)b * CONV_DIM + d0 + c) * 4 + (u + 4)];
        }
    }
    u16 out[8];
#pragma unroll
    for (int c = 0; c < 8; ++c) {
        float s = acc[c] / (1.f + __expf(-acc[c]));
        out[c] = f2bf(s);
    }
    uint4 o4;
    o4.x = out[0] | ((unsigned)out[1] << 16);
    o4.y = out[2] | ((unsigned)out[3] << 16);
    o4.z = out[4] | ((unsigned)out[5] << 16);
    o4.w = out[6] | ((unsigned)out[7] << 16);
    *(uint4*)&qkvc[(size_t)row * CONV_DIM + d0] = o4;
}

// ---------------- q/k L2 normalize in place (bf16) ----------------
__global__ __launch_bounds__(256) void qknorm_kernel(u16* __restrict__ qkvc) {
    const int gid  = blockIdx.x * 4 + (threadIdx.x >> 6);
    const int lane = threadIdx.x & 63;
    const int row  = gid >> 5;
    const int h    = gid & 31;
    u16* p = qkvc + (size_t)row * CONV_DIM + h * 128;
    ushort2 vb = *(ushort2*)&p[lane * 2];
    float v0 = bf2f(vb.x), v1 = bf2f(vb.y);
    float ss = v0 * v0 + v1 * v1;
#pragma unroll
    for (int off = 32; off; off >>= 1) ss += __shfl_xor(ss, off);
    float scale = 1.f / fmaxf(sqrtf(ss), 1e-12f);
    ushort2 r;
    r.x = f2bf(v0 * scale);
    r.y = f2bf(v1 * scale);
    *(ushort2*)&p[lane * 2] = r;
}

// ---------------- K1: per-chunk gate prefix (wave scan, CH=64) ----------------
__global__ __launch_bounds__(64) void gates_kernel(const float* __restrict__ g,
                                                   const float* __restrict__ beta_,
                                                   float* __restrict__ gcum,
                                                   float* __restrict__ qsb,
                                                   float* __restrict__ wkb,
                                                   float* __restrict__ dLb) {
    const int bh = blockIdx.x, c = blockIdx.y;
    const int b = bh >> 5, h = bh & 31;
    const int t = threadIdx.x;
    const int row = b * TT + c * CH + t;
    float G = g[(size_t)row * 32 + h];
#pragma unroll
    for (int off = 1; off < 64; off <<= 1) {
        float x = __shfl_up(G, off);
        if (t >= off) G += x;
    }
    float GL = __shfl(G, 63);
    int oidx = bh * TT + c * CH + t;
    gcum[oidx] = G;
    qsb[oidx] = __expf(G);
    wkb[oidx] = __expf(GL - G) * beta_[(size_t)row * 32 + h];
    if (t == 0) dLb[bh * NCHUNK + c] = __expf(GL);
}

// ---------------- kT transpose: qkvc k-section -> kT[B][NK][DK][T] ----------------
__global__ __launch_bounds__(256) void ktrans_kernel(const u16* __restrict__ qkvc,
                                                     u16* __restrict__ kT) {
    const int id = blockIdx.x;
    const int tt = id & 31, dkh = (id >> 5) & 1, hk = (id >> 6) & 15, b = id >> 10;
    const int t0 = tt * 64, dk0 = dkh * 64;
    __shared__ __align__(16) u16 tile[64 * 68];
#pragma unroll
    for (int it = 0; it < 2; ++it) {
        int idx = it * 256 + threadIdx.x;
        int tl = idx >> 3, c8 = (idx & 7) * 8;
        uint4 v = *(const uint4*)&qkvc[(size_t)(b * TT + t0 + tl) * CONV_DIM + KEY_DIM + hk * 128 + dk0 + c8];
        lds_st8(&tile[tl * 68 + c8], v);
    }
    __syncthreads();
#pragma unroll
    for (int it = 0; it < 2; ++it) {
        int idx = it * 256 + threadIdx.x;
        int dkl = idx >> 3, t8 = (idx & 7) * 8;
        unsigned w[4];
#pragma unroll
        for (int p = 0; p < 4; ++p) {
            unsigned lo = tile[(t8 + 2 * p) * 68 + dkl];
            unsigned hi = tile[(t8 + 2 * p + 1) * 68 + dkl];
            w[p] = lo | (hi << 16);
        }
        *(uint4*)&kT[((size_t)((b * 16 + hk) * 128 + dk0 + dkl)) * TT + t0 + t8] =
            make_uint4(w[0], w[1], w[2], w[3]);
    }
}

// ---------------- K2: chunk state pass + inter output (MFMA) ----------------
__global__ __launch_bounds__(256) void chunk_state_kernel(const u16* __restrict__ qkvc,
                                                          const u16* __restrict__ kT,
                                                          const float* __restrict__ qsb,
                                                          const float* __restrict__ wkb,
                                                          const float* __restrict__ dLb,
                                                          const float* __restrict__ rec_state,
                                                          const int* __restrict__ input_pos,
                                                          u16* __restrict__ o) {
    const int b = blockIdx.x, h = blockIdx.y, dvs = blockIdx.z;
    const int tid = threadIdx.x, lane = tid & 63, wave = tid >> 6;
    const int l15 = lane & 15, quad = lane >> 4;
    const int hq = h >> 1, bh = b * 32 + h;
    const float keep = (input_pos[0] == 0) ? 0.f : 1.f;

    __shared__ __align__(16) u16 sQ[64 * 132];
    __shared__ __align__(16) u16 sKT[128 * 68];
    __shared__ __align__(16) u16 sR[32 * 132];
    __shared__ float sQS[64];

    f32x4 st[2][2];
#pragma unroll
    for (int i = 0; i < 2; ++i)
#pragma unroll
        for (int j = 0; j < 2; ++j)
#pragma unroll
            for (int r = 0; r < 4; ++r) {
                int dv = dvs * 32 + i * 16 + quad * 4 + r;
                int dk = wave * 32 + j * 16 + l15;
                st[i][j][r] = keep * rec_state[((size_t)(bh * 128 + dk)) * 128 + dv];
            }

    for (int c = 0; c < NCHUNK; ++c) {
        const int t0 = c * CH;
#pragma unroll
        for (int i = 0; i < 2; ++i)
#pragma unroll
            for (int j = 0; j < 2; ++j)
#pragma unroll
                for (int r = 0; r < 4; ++r)
                    sR[(i * 16 + quad * 4 + r) * 132 + wave * 32 + j * 16 + l15] = f2bf(st[i][j][r]);
#pragma unroll
        for (int it = 0; it < 4; ++it) {
            int idx = it * 256 + tid;
            int t = idx >> 4, c8 = (idx & 15) * 8;
            uint4 v = *(const uint4*)&qkvc[(size_t)(b * TT + t0 + t) * CONV_DIM + hq * 128 + c8];
            lds_st8(&sQ[t * 132 + c8], v);
        }
        if (tid < 64) sQS[tid] = qsb[bh * TT + t0 + tid];
        __syncthreads();
        {
            f32x4 ao[2] = {(f32x4)0.0f, (f32x4)0.0f};
#pragma unroll
            for (int kk = 0; kk < 4; ++kk) {
                bf16x8 af = lds_ld8(&sQ[(wave * 16 + l15) * 132 + kk * 32 + quad * 8]);
                bf16x8 b0 = lds_ld8(&sR[(l15) * 132 + kk * 32 + quad * 8]);
                bf16x8 b1 = lds_ld8(&sR[(16 + l15) * 132 + kk * 32 + quad * 8]);
                ao[0] = __builtin_amdgcn_mfma_f32_16x16x32_bf16(af, b0, ao[0], 0, 0, 0);
                ao[1] = __builtin_amdgcn_mfma_f32_16x16x32_bf16(af, b1, ao[1], 0, 0, 0);
            }
#pragma unroll
            for (int j = 0; j < 2; ++j)
#pragma unroll
                for (int r = 0; r < 4; ++r) {
                    int t = wave * 16 + quad * 4 + r;
                    int dv = dvs * 32 + j * 16 + l15;
                    o[((size_t)(b * TT + t0 + t) * 32 + h) * 128 + dv] = f2bf(ao[j][r] * sQS[t]);
                }
        }
        __syncthreads();
#pragma unroll
        for (int it = 0; it < 4; ++it) {
            int idx = it * 256 + tid;
            int dk = idx >> 3, t8 = (idx & 7) * 8;
            uint4 v = *(const uint4*)&kT[((size_t)((b * 16 + hq) * 128 + dk)) * TT + t0 + t8];
            lds_st8(&sKT[dk * 68 + t8], v);
        }
        {
            int t = tid >> 2, dvo = (tid & 3) * 8;
            float w = wkb[bh * TT + t0 + t];
            BF8 v;
            v.u4 = *(const uint4*)&qkvc[(size_t)(b * TT + t0 + t) * CONV_DIM + 2 * KEY_DIM + h * 128 + dvs * 32 + dvo];
#pragma unroll
            for (int u = 0; u < 8; ++u)
                sR[(dvo + u) * 68 + t] = f2bf(bf2f(v.s[u]) * w);
        }
        __syncthreads();
        {
            float d = dLb[bh * NCHUNK + c];
#pragma unroll
            for (int i = 0; i < 2; ++i)
#pragma unroll
                for (int j = 0; j < 2; ++j)
#pragma unroll
                    for (int r = 0; r < 4; ++r) st[i][j][r] *= d;
#pragma unroll
            for (int kk = 0; kk < 2; ++kk) {
                bf16x8 af[2], bfv[2];
#pragma unroll
                for (int i = 0; i < 2; ++i)
                    af[i] = lds_ld8(&sR[(i * 16 + l15) * 68 + kk * 32 + quad * 8]);
#pragma unroll
                for (int j = 0; j < 2; ++j)
                    bfv[j] = lds_ld8(&sKT[(wave * 32 + j * 16 + l15) * 68 + kk * 32 + quad * 8]);
#pragma unroll
                for (int i = 0; i < 2; ++i)
#pragma unroll
                    for (int j = 0; j < 2; ++j)
                        st[i][j] = __builtin_amdgcn_mfma_f32_16x16x32_bf16(af[i], bfv[j], st[i][j], 0, 0, 0);
            }
        }
        __syncthreads();
    }
}

// ---------------- K3: intra-chunk causal attention (MFMA), adds into o ----------------
__global__ __launch_bounds__(256) void chunk_intra_kernel(const u16* __restrict__ qkvc,
                                                          const float* __restrict__ gcum,
                                                          const float* __restrict__ beta_,
                                                          u16* __restrict__ o) {
    const int b = blockIdx.x, h = blockIdx.y, c = blockIdx.z;
    const int tid = threadIdx.x, lane = tid & 63, wave = tid >> 6;
    const int l15 = lane & 15, quad = lane >> 4;
    const int hq = h >> 1, bh = b * 32 + h;
    const int t0 = c * CH;

    __shared__ __align__(16) u16 sQ[64 * 132];
    __shared__ __align__(16) u16 sK[64 * 132];
    __shared__ __align__(16) u16 sVT[128 * 68];
    __shared__ float sG[64];
    __shared__ float sB[64];

#pragma unroll
    for (int it = 0; it < 4; ++it) {
        int idx = it * 256 + tid;
        int t = idx >> 4, c8 = (idx & 15) * 8;
        size_t rbase = (size_t)(b * TT + t0 + t) * CONV_DIM;
        lds_st8(&sQ[t * 132 + c8], *(const uint4*)&qkvc[rbase + hq * 128 + c8]);
        lds_st8(&sK[t * 132 + c8], *(const uint4*)&qkvc[rbase + KEY_DIM + hq * 128 + c8]);
    }
    if (tid < 64) {
        sG[tid] = gcum[bh * TT + t0 + tid];
        sB[tid] = beta_[(size_t)(b * TT + t0 + tid) * 32 + h];
    }
    __syncthreads();
    const int wm = (wave & 1) * 32, wn = (wave >> 1) * 32;
    f32x4 acc[2][2];
#pragma unroll
    for (int i = 0; i < 2; ++i)
#pragma unroll
        for (int j = 0; j < 2; ++j) acc[i][j] = (f32x4)0.0f;
#pragma unroll
    for (int kk = 0; kk < 4; ++kk) {
        bf16x8 af[2], bfv[2];
#pragma unroll
        for (int i = 0; i < 2; ++i) {
            af[i]  = lds_ld8(&sQ[(wm + i * 16 + l15) * 132 + kk * 32 + quad * 8]);
            bfv[i] = lds_ld8(&sK[(wn + i * 16 + l15) * 132 + kk * 32 + quad * 8]);
        }
#pragma unroll
        for (int i = 0; i < 2; ++i)
#pragma unroll
            for (int j = 0; j < 2; ++j)
                acc[i][j] = __builtin_amdgcn_mfma_f32_16x16x32_bf16(af[i], bfv[j], acc[i][j], 0, 0, 0);
    }
    __syncthreads();
#pragma unroll
    for (int i = 0; i < 2; ++i)
#pragma unroll
        for (int j = 0; j < 2; ++j)
#pragma unroll
            for (int r = 0; r < 4; ++r) {
                int t = wm + i * 16 + quad * 4 + r;
                int s = wn + j * 16 + l15;
                float av = 0.f;
                if (s <= t) av = __expf(sG[t] - sG[s]) * sB[s] * acc[i][j][r];
                ((u16*)sQ)[t * 68 + s] = f2bf(av);
            }
#pragma unroll
    for (int it = 0; it < 4; ++it) {
        int idx = it * 256 + tid;
        int t = idx >> 4, c8 = (idx & 15) * 8;
        lds_st8(&sK[t * 132 + c8],
                *(const uint4*)&qkvc[(size_t)(b * TT + t0 + t) * CONV_DIM + 2 * KEY_DIM + h * 128 + c8]);
    }
    __syncthreads();
    {
        int dv = (wave & 1) * 64 + lane;
        int tb = (wave >> 1) * 32;
#pragma unroll
        for (int tc = 0; tc < 4; ++tc) {
            int t8 = tb + tc * 8;
            unsigned w[4];
#pragma unroll
            for (int p = 0; p < 4; ++p) {
                unsigned lo = sK[(t8 + 2 * p) * 132 + dv];
                unsigned hi = sK[(t8 + 2 * p + 1) * 132 + dv];
                w[p] = lo | (hi << 16);
            }
            lds_st8(&sVT[dv * 68 + t8], make_uint4(w[0], w[1], w[2], w[3]));
        }
    }
    __syncthreads();
    const int wm2 = (wave & 1) * 32, wn2 = (wave >> 1) * 64;
    f32x4 oacc[2][4];
#pragma unroll
    for (int i = 0; i < 2; ++i)
#pragma unroll
        for (int j = 0; j < 4; ++j) oacc[i][j] = (f32x4)0.0f;
#pragma unroll
    for (int kk = 0; kk < 2; ++kk) {
        bf16x8 af[2], bfv[4];
#pragma unroll
        for (int i = 0; i < 2; ++i)
            af[i] = lds_ld8(&((u16*)sQ)[(wm2 + i * 16 + l15) * 68 + kk * 32 + quad * 8]);
#pragma unroll
        for (int j = 0; j < 4; ++j)
            bfv[j] = lds_ld8(&sVT[(wn2 + j * 16 + l15) * 68 + kk * 32 + quad * 8]);
#pragma unroll
        for (int i = 0; i < 2; ++i)
#pragma unroll
            for (int j = 0; j < 4; ++j)
                oacc[i][j] = __builtin_amdgcn_mfma_f32_16x16x32_bf16(af[i], bfv[j], oacc[i][j], 0, 0, 0);
    }
#pragma unroll
    for (int i = 0; i < 2; ++i)
#pragma unroll
        for (int j = 0; j < 4; ++j)
#pragma unroll
            for (int r = 0; r < 4; ++r) {
                int t = wm2 + i * 16 + quad * 4 + r;
                int dv = wn2 + j * 16 + l15;
                size_t addr = ((size_t)(b * TT + t0 + t) * 32 + h) * 128 + dv;
                o[addr] = f2bf(oacc[i][j][r] + bf2f(o[addr]));
            }
}

// ---------------- gated RMSNorm: o *= silu(z); rmsnorm; -> bf16 ----------------
__global__ __launch_bounds__(256) void gnorm_kernel(const u16* __restrict__ o,
                                                    const u16* __restrict__ zb,
                                                    const float* __restrict__ norm_w,
                                                    u16* __restrict__ ob) {
    const int gid  = blockIdx.x * 4 + (threadIdx.x >> 6);
    const int lane = threadIdx.x & 63;
    const int row  = gid >> 5;
    const int h    = gid & 31;
    const size_t base = ((size_t)row * NVH + h) * DVD;
    ushort2 oraw = *(const ushort2*)&o[base + lane * 2];
    float o0 = bf2f(oraw.x), o1 = bf2f(oraw.y);
    float z0 = bf2f(zb[base + lane * 2]);
    float z1 = bf2f(zb[base + lane * 2 + 1]);
    o0 *= z0 / (1.f + __expf(-z0));
    o1 *= z1 / (1.f + __expf(-z1));
    float ss = o0 * o0 + o1 * o1;
#pragma unroll
    for (int off = 32; off; off >>= 1) ss += __shfl_xor(ss, off);
    float scale = rsqrtf(ss * (1.f / 128.f) + 1e-6f);
    float w0 = norm_w[lane * 2], w1 = norm_w[lane * 2 + 1];
    ushort2 r;
    r.x = f2bf(o0 * scale * w0);
    r.y = f2bf(o1 * scale * w1);
    *(ushort2*)&ob[base + lane * 2] = r;
}

extern "C" void kernel_launch(void* const* d_in, const int* in_sizes, int n_in,
                              void* d_out, int out_size, void* d_ws, size_t ws_size,
                              hipStream_t stream) {
    const float* x         = (const float*)d_in[0];
    const int*   input_pos = (const int*)d_in[1];
    const float* W_qkv     = (const float*)d_in[2];
    const float* W_z       = (const float*)d_in[3];
    const float* W_b       = (const float*)d_in[4];
    const float* W_a       = (const float*)d_in[5];
    const float* conv_w    = (const float*)d_in[6];
    const float* dt_bias   = (const float*)d_in[7];
    const float* A_log     = (const float*)d_in[8];
    const float* norm_w    = (const float*)d_in[9];
    const float* W_out     = (const float*)d_in[10];
    const float* conv_state = (const float*)d_in[11];
    const float* rec_state  = (const float*)d_in[12];
    float* out = (float*)d_out;

    const size_t REQUIRED = 168820736;   // 161 MiB
    if (ws_size < REQUIRED) {
        float mib = (float)((double)ws_size / 1048576.0);
        fill_kernel<<<(out_size + 255) / 256, 256, 0, stream>>>(out, mib, out_size);
        return;
    }

    const size_t MI = 1048576;
    char* ws = (char*)d_ws;
    u16* xb    = (u16*)(ws);
    u16* wqkvb = (u16*)(ws + 16 * MI);
    u16* wzb   = (u16*)(ws + 48 * MI);
    u16* wbab  = (u16*)(ws + 16 * MI);      // 128x2048 bf16, alias dead wqkvb
    float* bgs = (float*)(ws + 17 * MI);    // 4096x128 fp32 scores
    u16* qkvc  = (u16*)(ws);
    u16* ob    = (u16*)(ws);
    u16* woutb = (u16*)(ws + 32 * MI);
    u16* zb    = (u16*)(ws + 64 * MI);
    u16* qkvb  = (u16*)(ws + 96 * MI);
    u16* o     = (u16*)(ws + 96 * MI);
    u16* kT    = (u16*)(ws + 128 * MI);
    float* gcum = (float*)(ws + 144 * MI);
    float* qsb  = (float*)(ws + 144 * MI + 524288);
    float* wkb  = (float*)(ws + 145 * MI);
    float* dLb  = (float*)(ws + 145 * MI + 524288);
    float* beta = (float*)(ws + 160 * MI);
    float* g    = (float*)(ws + 160 * MI + 524288);

    // 1. casts
    cast_kernel<<<8192,  256, 0, stream>>>(x,     xb,    2097152);
    cast_kernel<<<16384, 256, 0, stream>>>(W_qkv, wqkvb, 4194304);
    cast_kernel<<<8192,  256, 0, stream>>>(W_z,   wzb,   2097152);

    // 2. big projections: R2-winner 256x256 counted-vmcnt pipeline
    gemm_nt_256<1><<<dim3(32, 16), 512, 0, stream>>>(xb, wqkvb, qkvb, MROWS, CONV_DIM, CDIM);
    gemm_nt_256<1><<<dim3(16, 16), 512, 0, stream>>>(xb, wzb,   zb,   MROWS, VAL_DIM,  CDIM);

    // 3. beta/g via MFMA GEMM (into dead wqkvb region; before conv clobbers xb)
    cast_kernel<<<256, 256, 0, stream>>>(W_b, wbab, 16384);
    cast_kernel<<<256, 256, 0, stream>>>(W_a, wbab + 65536, 16384);
    hipMemsetAsync(wbab + 131072, 0, 131072 * sizeof(u16), stream);   // pad rows 64..127
    gemm_nt<0><<<dim3(1, 32), 256, 0, stream>>>(xb, wbab, bgs, MROWS, 128, CDIM);
    bg_epilogue<<<1024, 256, 0, stream>>>(bgs, dt_bias, A_log, beta, g);

    // 4. conv + silu (vectorized, clobbers [0,64Mi)), q/k norm
    conv_silu_kernel<<<dim3(4, 4096), 256, 0, stream>>>(qkvb, conv_w, conv_state, input_pos, qkvc);
    qknorm_kernel<<<32768, 256, 0, stream>>>(qkvc);

    // 5. chunked recurrence
    gates_kernel<<<dim3(64, NCHUNK), 64, 0, stream>>>(g, beta, gcum, qsb, wkb, dLb);
    ktrans_kernel<<<2048, 256, 0, stream>>>(qkvc, kT);
    chunk_state_kernel<<<dim3(BB, NVH, 4), 256, 0, stream>>>(qkvc, kT, qsb, wkb, dLb,
                                                             rec_state, input_pos, o);
    chunk_intra_kernel<<<dim3(BB, NVH, NCHUNK), 256, 0, stream>>>(qkvc, gcum, beta, o);

    // 6. W_out cast (into dead qkvc region) + gated RMSNorm
    cast_kernel<<<8192, 256, 0, stream>>>(W_out, woutb, 2097152);
    gnorm_kernel<<<32768, 256, 0, stream>>>(o, zb, norm_w, ob);

    // 7. output projection (fp32 out; N=2048, 128-tile kernel, conflict-free)
    gemm_nt<0><<<dim3(16, 32), 256, 0, stream>>>(ob, woutb, out, MROWS, CDIM, VAL_DIM);
}